// Round 3
// baseline (1986.814 us; speedup 1.0000x reference)
//
#include <hip/hip_runtime.h>
#include <hip/hip_bf16.h>
#include <stdint.h>

typedef __hip_bfloat16 bf16;
typedef unsigned long long u64;
typedef unsigned short u16;

static __device__ __forceinline__ float b2f(bf16 v) { return __bfloat162float(v); }

// dtype-flexible input read: f32 flag chosen at runtime by k_probe
static __device__ __forceinline__ float ldin(const void* p, long i, int f32) {
    return f32 ? ((const float*)p)[i] : __bfloat162float(((const bf16*)p)[i]);
}

// ---------------- control block ----------------
// ctl[0] = diag bits; ctl[1] = f32 flag
__global__ void k_zero_ctl(unsigned* ctl) {
    if (threadIdx.x < 64) ctl[threadIdx.x] = 0u;
}

// probe input dtype: bf16-interpret even halves of x; sane -> bf16, garbage -> f32
__global__ void k_probe(const void* x, unsigned* ctl) {
    int tid = threadIdx.x;
    int good = 0;
    for (int i = tid; i < 1024; i += 256) {
        float v = __bfloat162float(((const bf16*)x)[2 * i]);
        float a = fabsf(v);
        if (v == 0.0f || (isfinite(v) && a >= 1e-4f && a <= 100.0f)) good++;
    }
    __shared__ int s[256];
    s[tid] = good; __syncthreads();
    for (int st = 128; st > 0; st >>= 1) {
        if (tid < st) s[tid] += s[tid + st];
        __syncthreads();
    }
    if (tid == 0) ctl[1] = (s[0] >= 700) ? 0u : 1u;   // sane bf16 -> 0, else f32 -> 1
}

// write sentinel value to all outputs (dtype per flag)
__global__ void k_sentinel(void* outv, const unsigned* ctl, float val) {
    int i = blockIdx.x * 256 + threadIdx.x;
    if (i >= 64000) return;
    if (ctl[1]) ((float*)outv)[i] = val;
    else ((bf16*)outv)[i] = __float2bfloat16(val);
}

// ---------------- checkers ----------------
__global__ void k_chk_f64(const double* p, int n, int bit, unsigned* ctl) {
    int i = blockIdx.x * 256 + threadIdx.x;
    if (i < n && !isfinite(p[i])) atomicOr(&ctl[0], 1u << bit);
}
__global__ void k_chk_u16(const u16* p, int n, unsigned maxv, int bit, unsigned* ctl) {
    int i = blockIdx.x * 256 + threadIdx.x;
    if (i < n && (unsigned)p[i] > maxv) atomicOr(&ctl[0], 1u << bit);
}

// ---------------- zero helper ----------------
__global__ void k_zero32(unsigned* p, int n) {
    int i = blockIdx.x * 256 + threadIdx.x;
    if (i < n) p[i] = 0u;
}

// ---------------- weight prep ----------------
__global__ void k_sign_w1(const void* w, float* ws, int n, const unsigned* ctl) {
    int f32 = ctl[1];
    int i = blockIdx.x * 256 + threadIdx.x;
    if (i < n) {
        float v = ldin(w, i, f32);
        ws[i] = (v > 0.f) ? 1.f : ((v < 0.f) ? -1.f : 0.f);
    }
}

// conv weights (Co, 64, 41) -> packed [co][k] uint2, bit c of word c/32
__global__ void k_pack_convw(const void* w, uint2* wp, int Co, const unsigned* ctl) {
    int f32 = ctl[1];
    int t = blockIdx.x * 256 + threadIdx.x;
    if (t >= Co * 41) return;
    int co = t / 41, k = t % 41;
    unsigned w0 = 0, w1 = 0;
    for (int c = 0; c < 32; c++)
        if (ldin(w, (co * 64 + c) * 41 + k, f32) > 0.f) w0 |= (1u << c);
    for (int c = 0; c < 32; c++)
        if (ldin(w, (co * 64 + 32 + c) * 41 + k, f32) > 0.f) w1 |= (1u << c);
    wp[t] = make_uint2(w0, w1);
}

// fc weights (rows, F) -> packed words along F
__global__ void k_pack_rows_b(const void* w, unsigned* wp, int rows, int F, const unsigned* ctl) {
    int f32 = ctl[1];
    int Fw = F >> 5;
    int t = blockIdx.x * 256 + threadIdx.x;
    if (t >= rows * Fw) return;
    int r = t / Fw, wi = t % Fw;
    unsigned m = 0;
    for (int j = 0; j < 32; j++)
        if (ldin(w, (long)r * F + wi * 32 + j, f32) > 0.f) m |= (1u << j);
    wp[t] = m;
}

// ---------------- bn0: f64 stats over x (N=64, C=3, L=16000) ----------------
__global__ void k_bn0_stats(const void* x, double* part, const unsigned* ctl) {
    int f32 = ctl[1];
    int c = blockIdx.y, s = blockIdx.x, tid = threadIdx.x;  // grid (32, 3)
    double s1 = 0, s2 = 0;
    for (int n = 0; n < 64; n++) {
        long base = (long)(n * 3 + c) * 16000;
        for (int l = s * 256 + tid; l < 16000; l += 32 * 256) {
            double v = (double)ldin(x, base + l, f32);
            s1 += v; s2 += v * v;
        }
    }
    __shared__ double a1[256], a2[256];
    a1[tid] = s1; a2[tid] = s2;
    __syncthreads();
    for (int st = 128; st > 0; st >>= 1) {
        if (tid < st) { a1[tid] += a1[tid + st]; a2[tid] += a2[tid + st]; }
        __syncthreads();
    }
    if (tid == 0) { part[(c * 32 + s) * 2] = a1[0]; part[(c * 32 + s) * 2 + 1] = a2[0]; }
}

__global__ void k_bn0_fin(const double* part, const void* g, const void* b, double2* bnp0,
                          const unsigned* ctl) {
    int f32 = ctl[1];
    int c = threadIdx.x;
    if (c >= 3) return;
    double s1 = 0, s2 = 0;
    for (int s = 0; s < 32; s++) { s1 += part[(c * 32 + s) * 2]; s2 += part[(c * 32 + s) * 2 + 1]; }
    double M = 64.0 * 16000.0;
    double mu = s1 / M, var = s2 / M - mu * mu;
    double A = (double)ldin(g, c, f32) / sqrt(var + 1e-5);
    bnp0[c] = make_double2(A, (double)ldin(b, c, f32) - mu * A);
}

// ---------------- conv1 (f64, two-pass) ----------------
__device__ __forceinline__ void conv1_tile_load(const void* __restrict__ x,
                                                const double2* __restrict__ bnp0,
                                                int n, int base, int f32, double (*xt)[272]) {
    for (int i = threadIdx.x; i < 816; i += 256) {
        int c = i / 272, j = i % 272;
        int pos = base + j;
        double v = 0.0;
        if (pos < 16000) {
            double2 p = bnp0[c];
            v = (double)ldin(x, (long)(n * 3 + c) * 16000 + pos, f32) * p.x + p.y;
            v = fmin(fmax(v, -1.0), 1.0);   // hardtanh
        }
        xt[c][j] = v;
    }
}

__device__ __forceinline__ void conv1_dot(const double (*xt)[272], const float* __restrict__ ws,
                                          int lane, int co0, double yp[4]) {
    double acc[4][3] = {};
    for (int c = 0; c < 3; c++) {
        for (int kc = 0; kc < 40; kc += 4) {
            double xv[9];
#pragma unroll
            for (int i = 0; i < 9; i++) xv[i] = xt[c][3 * lane + 2 * kc + i];
#pragma unroll
            for (int kk = 0; kk < 4; kk++) {
#pragma unroll
                for (int j = 0; j < 4; j++) {
                    double wv = (double)ws[(co0 + j) * 123 + c * 41 + kc + kk];
                    acc[j][0] = fma(wv, xv[2 * kk], acc[j][0]);
                    acc[j][1] = fma(wv, xv[2 * kk + 1], acc[j][1]);
                    acc[j][2] = fma(wv, xv[2 * kk + 2], acc[j][2]);
                }
            }
        }
        double x0 = xt[c][3 * lane + 80], x1 = xt[c][3 * lane + 81], x2 = xt[c][3 * lane + 82];
#pragma unroll
        for (int j = 0; j < 4; j++) {
            double wv = (double)ws[(co0 + j) * 123 + c * 41 + 40];
            acc[j][0] = fma(wv, x0, acc[j][0]);
            acc[j][1] = fma(wv, x1, acc[j][1]);
            acc[j][2] = fma(wv, x2, acc[j][2]);
        }
    }
#pragma unroll
    for (int j = 0; j < 4; j++)
        yp[j] = fmax(fmax(acc[j][0], acc[j][1]), acc[j][2]);   // maxpool3 (bias cancels in bn1)
}

__global__ __launch_bounds__(256) void k_conv1_p1(const void* __restrict__ x,
                                                  const double2* __restrict__ bnp0,
                                                  const float* __restrict__ ws,
                                                  double* __restrict__ part1,
                                                  const unsigned* ctl) {
    __shared__ double xt[3][272];
    int f32 = ctl[1];
    int n = blockIdx.y, bx = blockIdx.x;
    conv1_tile_load(x, bnp0, n, bx * 192, f32, xt);
    __syncthreads();
    int lane = threadIdx.x & 63, wave = threadIdx.x >> 6;
    int co0 = blockIdx.z * 16 + wave * 4;
    int lp = bx * 64 + lane;
    double yp[4];
    conv1_dot(xt, ws, lane, co0, yp);
    bool ok = lp < 5306;
#pragma unroll
    for (int j = 0; j < 4; j++) {
        double s = ok ? yp[j] : 0.0;
        double q = ok ? yp[j] * yp[j] : 0.0;
        for (int off = 32; off > 0; off >>= 1) {
            s += __shfl_down(s, off, 64);
            q += __shfl_down(q, off, 64);
        }
        if (lane == 0) {
            int idx = (((co0 + j) * 83 + bx) * 64 + n) * 2;
            part1[idx] = s; part1[idx + 1] = q;
        }
    }
}

__global__ void k_fin1(const double* part1, const void* g, const void* b, double2* bnp1,
                       const unsigned* ctl) {
    int f32 = ctl[1];
    int c = threadIdx.x;  // 64
    double s = 0, q = 0;
    for (int bx = 0; bx < 83; bx++)
        for (int n = 0; n < 64; n++) {
            int idx = ((c * 83 + bx) * 64 + n) * 2;
            s += part1[idx]; q += part1[idx + 1];
        }
    double M = 64.0 * 5306.0;
    double mu = s / M, var = q / M - mu * mu;
    double A = (double)ldin(g, c, f32) / sqrt(var + 1e-5);
    bnp1[c] = make_double2(A, (double)ldin(b, c, f32) - mu * A);
}

__global__ __launch_bounds__(256) void k_conv1_p2(const void* __restrict__ x,
                                                  const double2* __restrict__ bnp0,
                                                  const float* __restrict__ ws,
                                                  const double2* __restrict__ bnp1,
                                                  unsigned* __restrict__ x2p,
                                                  const unsigned* ctl) {
    __shared__ double xt[3][272];
    __shared__ unsigned sl[4][64];
    int f32 = ctl[1];
    int n = blockIdx.y, bx = blockIdx.x;
    conv1_tile_load(x, bnp0, n, bx * 192, f32, xt);
    __syncthreads();
    int lane = threadIdx.x & 63, wave = threadIdx.x >> 6;
    int co0 = blockIdx.z * 16 + wave * 4;
    double yp[4];
    conv1_dot(xt, ws, lane, co0, yp);
    unsigned bits = 0;
#pragma unroll
    for (int j = 0; j < 4; j++) {
        double2 p = bnp1[co0 + j];
        if (yp[j] * p.x + p.y > 0.0) bits |= (1u << j);
    }
    sl[wave][lane] = bits;
    __syncthreads();
    if (threadIdx.x < 64) {
        int lp = bx * 64 + threadIdx.x;
        if (lp < 5306) {
            int l = threadIdx.x;
            unsigned slice = sl[0][l] | (sl[1][l] << 4) | (sl[2][l] << 8) | (sl[3][l] << 12);
            int z = blockIdx.z;
            atomicOr(&x2p[(n * 5306 + lp) * 2 + (z >> 1)], slice << ((z & 1) * 16));
        }
    }
}

// ---------------- binary conv (Ci=64) + fused maxpool3 -> pooled-min popcount ----------------
__global__ __launch_bounds__(256) void k_conv_bin(const uint2* __restrict__ xp,
                                                  const uint2* __restrict__ wp,
                                                  u16* __restrict__ mout,
                                                  int Lp, int Lin, int Co) {
    int n = blockIdx.y;
    int lane = threadIdx.x & 63, wave = threadIdx.x >> 6;
    int co0 = blockIdx.z * 16 + wave * 4;
    int base = blockIdx.x * 192;
    int lp = blockIdx.x * 64 + lane;

    __shared__ uint2 xt[272];
    for (int i = threadIdx.x; i < 272; i += 256) {
        int pos = base + i;
        xt[i] = (pos < Lin) ? xp[(size_t)n * Lin + pos] : make_uint2(0u, 0u);
    }
    __syncthreads();

    int acc[4][3] = {};
    for (int k = 0; k < 41; k++) {
        uint2 xa = xt[3 * lane + 2 * k];
        uint2 xb = xt[3 * lane + 2 * k + 1];
        uint2 xc = xt[3 * lane + 2 * k + 2];
#pragma unroll
        for (int j = 0; j < 4; j++) {
            uint2 w = wp[(co0 + j) * 41 + k];
            acc[j][0] += __popc(w.x ^ xa.x) + __popc(w.y ^ xa.y);
            acc[j][1] += __popc(w.x ^ xb.x) + __popc(w.y ^ xb.y);
            acc[j][2] += __popc(w.x ^ xc.x) + __popc(w.y ^ xc.y);
        }
    }
    if (lp < Lp) {
#pragma unroll
        for (int j = 0; j < 4; j++) {
            int m = min(min(acc[j][0], acc[j][1]), acc[j][2]);   // min m == max y
            mout[((size_t)n * Co + co0 + j) * Lp + lp] = (u16)m;
        }
    }
}

// ---------------- exact integer BN stats over m (u16) ----------------
__global__ void k_mstats(const u16* __restrict__ m, int L, u64* __restrict__ part) {
    int c = blockIdx.y, s = blockIdx.x, tid = threadIdx.x;  // grid (16, 64)
    u64 s1 = 0, s2 = 0;
    for (int n = 0; n < 64; n++) {
        const u16* p = m + ((size_t)(n * 64 + c)) * L;
        for (int l = s * 256 + tid; l < L; l += 16 * 256) {
            unsigned v = p[l];
            s1 += v; s2 += (u64)v * v;
        }
    }
    __shared__ u64 a1[256], a2[256];
    a1[tid] = s1; a2[tid] = s2;
    __syncthreads();
    for (int st = 128; st > 0; st >>= 1) {
        if (tid < st) { a1[tid] += a1[tid + st]; a2[tid] += a2[tid + st]; }
        __syncthreads();
    }
    if (tid == 0) { part[(c * 16 + s) * 2] = a1[0]; part[(c * 16 + s) * 2 + 1] = a2[0]; }
}

// y = K - 2m + bias; v = m*p + q; p = -2A, q = 2A*mu + beta; var_y = 4 var_m
__global__ void k_fin_m(const u64* part, double M, const void* g, const void* b, double2* pq,
                        const unsigned* ctl) {
    int f32 = ctl[1];
    int c = threadIdx.x;  // 64
    u64 s1 = 0, s2 = 0;
    for (int s = 0; s < 16; s++) { s1 += part[(c * 16 + s) * 2]; s2 += part[(c * 16 + s) * 2 + 1]; }
    double mu = (double)s1 / M;
    double varm = (double)s2 / M - mu * mu;
    double A = (double)ldin(g, c, f32) / sqrt(4.0 * varm + 1e-5);
    pq[c] = make_double2(-2.0 * A, 2.0 * A * mu + (double)ldin(b, c, f32));
}

__global__ void k_pack_m(const u16* __restrict__ m, const double2* __restrict__ pq,
                         uint2* __restrict__ xp, int L) {
    int n = blockIdx.y;
    int l = blockIdx.x * 256 + threadIdx.x;
    if (l >= L) return;
    unsigned w0 = 0, w1 = 0;
    for (int c = 0; c < 32; c++) {
        double2 p = pq[c];
        if ((double)m[((size_t)n * 64 + c) * L + l] * p.x + p.y > 0.0) w0 |= 1u << c;
    }
    for (int c = 0; c < 32; c++) {
        double2 p = pq[c + 32];
        if ((double)m[((size_t)n * 64 + c + 32) * L + l] * p.x + p.y > 0.0) w1 |= 1u << c;
    }
    xp[(size_t)n * L + l] = make_uint2(w0, w1);
}

// fc1 input: sign(2624 - 2*m5 + conv5_b), flatten (32,26)->832
__global__ void k_pack_fc1in(const u16* __restrict__ m5, const void* __restrict__ b5,
                             unsigned* __restrict__ x6p, const unsigned* ctl) {
    int f32 = ctl[1];
    int t = blockIdx.x * 64 + threadIdx.x;  // 26 x 64
    if (t >= 64 * 26) return;
    int n = t / 26, wi = t % 26;
    unsigned mask = 0;
    for (int j = 0; j < 32; j++) {
        int f = wi * 32 + j, c = f / 26, l = f % 26;
        double y = 2624.0 - 2.0 * (double)m5[(n * 32 + c) * 26 + l] + (double)ldin(b5, c, f32);
        if (y > 0.0) mask |= 1u << j;
    }
    x6p[n * 26 + wi] = mask;
}

__global__ void k_fc_acc(const unsigned* __restrict__ xp, const unsigned* __restrict__ wp,
                         u16* __restrict__ acc, int J, int W) {
    int n = blockIdx.y;
    int j = blockIdx.x * 256 + threadIdx.x;
    if (j >= J) return;
    unsigned a = 0;
    for (int w = 0; w < W; w++) a += __popc(xp[n * W + w] ^ wp[j * W + w]);
    acc[n * J + j] = (u16)a;
}

__global__ void k_fc_bn(const u16* __restrict__ acc, int J, const void* g, const void* b,
                        double2* __restrict__ pq, const unsigned* ctl) {
    int f32 = ctl[1];
    int j = blockIdx.x * 256 + threadIdx.x;
    if (j >= J) return;
    u64 s1 = 0, s2 = 0;
    for (int n = 0; n < 64; n++) { unsigned a = acc[n * J + j]; s1 += a; s2 += (u64)a * a; }
    double mu = (double)s1 / 64.0;
    double varm = (double)s2 / 64.0 - mu * mu;
    double A = (double)ldin(g, j, f32) / sqrt(4.0 * varm + 1e-5);
    pq[j] = make_double2(-2.0 * A, 2.0 * A * mu + (double)ldin(b, j, f32));
}

__global__ void k_pack_fc2in(const u16* __restrict__ acc1, const double2* __restrict__ pq5,
                             unsigned* __restrict__ x7p) {
    int t = blockIdx.x * 256 + threadIdx.x;  // 8 x 256 = 2048
    if (t >= 64 * 32) return;
    int n = t / 32, wi = t % 32;
    unsigned mask = 0;
    for (int j = 0; j < 32; j++) {
        int f = wi * 32 + j;
        double2 p = pq5[f];
        if ((double)acc1[n * 1024 + f] * p.x + p.y > 0.0) mask |= 1u << j;
    }
    x7p[t] = mask;
}

// bn6 + log_softmax; diag sentinel + non-finite sanitize; dtype per flag
__global__ void k_lsm(const u16* __restrict__ acc2, const double2* __restrict__ pq6,
                      const unsigned* ctl, void* outv) {
    int n = blockIdx.x, tid = threadIdx.x;
    int f32 = ctl[1];
    unsigned dg = ctl[0];
    if (dg) {
        int k = __ffs(dg) - 1;
        float sv = -(300.0f + 20.0f * (float)k);
#pragma unroll
        for (int i = 0; i < 4; i++) {
            int j = tid + i * 256;
            if (j < 1000) {
                if (f32) ((float*)outv)[n * 1000 + j] = sv;
                else ((bf16*)outv)[n * 1000 + j] = __float2bfloat16(sv);
            }
        }
        return;
    }
    __shared__ double red[256];
    double v[4];
    double mx = -1e300;
#pragma unroll
    for (int i = 0; i < 4; i++) {
        int j = tid + i * 256;
        if (j < 1000) {
            double2 p = pq6[j];
            v[i] = (double)acc2[n * 1000 + j] * p.x + p.y;
            mx = fmax(mx, v[i]);
        } else v[i] = -1e300;
    }
    red[tid] = mx; __syncthreads();
    for (int s = 128; s > 0; s >>= 1) {
        if (tid < s) red[tid] = fmax(red[tid], red[tid + s]);
        __syncthreads();
    }
    mx = red[0]; __syncthreads();
    double sum = 0.0;
#pragma unroll
    for (int i = 0; i < 4; i++) {
        int j = tid + i * 256;
        if (j < 1000) sum += exp(v[i] - mx);
    }
    red[tid] = sum; __syncthreads();
    for (int s = 128; s > 0; s >>= 1) {
        if (tid < s) red[tid] += red[tid + s];
        __syncthreads();
    }
    double ls = log(red[0]);
#pragma unroll
    for (int i = 0; i < 4; i++) {
        int j = tid + i * 256;
        if (j < 1000) {
            float r = (float)(v[i] - mx - ls);
            if (!isfinite(r)) r = -700.0f;      // impossible by construction; belt+braces
            if (f32) ((float*)outv)[n * 1000 + j] = r;
            else ((bf16*)outv)[n * 1000 + j] = __float2bfloat16(r);
        }
    }
}

extern "C" void kernel_launch(void* const* d_in, const int* in_sizes, int n_in,
                              void* d_out, int out_size, void* d_ws, size_t ws_size,
                              hipStream_t stream) {
    const void* x       = d_in[0];
    const void* bn0_g   = d_in[1];
    const void* bn0_b   = d_in[2];
    const void* conv1_w = d_in[3];
    const void* bn1_g   = d_in[5];
    const void* bn1_b   = d_in[6];
    const void* conv2_w = d_in[7];
    const void* bn2_g   = d_in[9];
    const void* bn2_b   = d_in[10];
    const void* conv3_w = d_in[11];
    const void* bn3_g   = d_in[13];
    const void* bn3_b   = d_in[14];
    const void* conv4_w = d_in[15];
    const void* bn4_g   = d_in[17];
    const void* bn4_b   = d_in[18];
    const void* conv5_w = d_in[19];
    const void* conv5_b = d_in[20];
    const void* fc1_w   = d_in[21];
    const void* bn5_g   = d_in[23];
    const void* bn5_b   = d_in[24];
    const void* fc2_w   = d_in[25];
    const void* bn6_g   = d_in[27];
    const void* bn6_b   = d_in[28];

    char* wsb = (char*)d_ws;
    size_t off = 0;
    auto alloc = [&](size_t bytes) -> void* {
        off = (off + 255) & ~(size_t)255;
        void* p = wsb + off;
        off += bytes;
        return p;
    };

    unsigned* ctl   = (unsigned*)alloc(256);           // [0]=diag bits, [1]=f32 flag
    unsigned* x2p   = (unsigned*)alloc(2716672);       // 5306*64 uint2 (zeroed, atomicOr)
    double*   part1 = (double*)alloc(5439488);         // 64*83*64*2 f64
    u16*      m2    = (u16*)alloc(14270464);           // 64*64*1742
    uint2*    x3p   = (uint2*)alloc(891904);
    u16*      m3    = (u16*)alloc(4538368);            // 64*64*554
    uint2*    x4p   = (uint2*)alloc(283648);
    u16*      m4    = (u16*)alloc(1294336);            // 64*64*158
    uint2*    x5p   = (uint2*)alloc(80896);
    u16*      m5    = (u16*)alloc(106496);             // 64*32*26
    unsigned* x6p   = (unsigned*)alloc(6656);
    u16*      acc1  = (u16*)alloc(131072);             // 64*1024
    unsigned* x7p   = (unsigned*)alloc(8192);
    u16*      acc2  = (u16*)alloc(128000);             // 64*1000
    float*    ws1   = (float*)alloc(31488);
    uint2*    w2p   = (uint2*)alloc(20992);
    uint2*    w3p   = (uint2*)alloc(20992);
    uint2*    w4p   = (uint2*)alloc(20992);
    uint2*    w5p   = (uint2*)alloc(10496);
    unsigned* fc1wp = (unsigned*)alloc(106496);
    unsigned* fc2wp = (unsigned*)alloc(128000);
    void*     partS = alloc(32768);                    // bn0 f64 / mstats u64 scratch
    double2*  bnp0  = (double2*)alloc(3 * 16);
    double2*  bnp1  = (double2*)alloc(64 * 16);
    double2*  pq2   = (double2*)alloc(64 * 16);
    double2*  pq3   = (double2*)alloc(64 * 16);
    double2*  pq4   = (double2*)alloc(64 * 16);
    double2*  pq5   = (double2*)alloc(1024 * 16);
    double2*  pq6   = (double2*)alloc(1000 * 16);
    size_t need = (off + 255) & ~(size_t)255;

    k_zero_ctl<<<1, 64, 0, stream>>>(ctl);
    k_probe<<<1, 256, 0, stream>>>(x, ctl);

    if (n_in != 29) {
        k_sentinel<<<250, 256, 0, stream>>>(d_out, ctl, -(3000.0f + (float)n_in));
        return;
    }
    if (ws_size < need) {
        k_sentinel<<<250, 256, 0, stream>>>(d_out, ctl, -1500.0f);
        return;
    }

    // --- weight prep ---
    k_sign_w1<<<31, 256, 0, stream>>>(conv1_w, ws1, 7872, ctl);
    k_pack_convw<<<11, 256, 0, stream>>>(conv2_w, w2p, 64, ctl);
    k_pack_convw<<<11, 256, 0, stream>>>(conv3_w, w3p, 64, ctl);
    k_pack_convw<<<11, 256, 0, stream>>>(conv4_w, w4p, 64, ctl);
    k_pack_convw<<<6, 256, 0, stream>>>(conv5_w, w5p, 32, ctl);
    k_pack_rows_b<<<104, 256, 0, stream>>>(fc1_w, fc1wp, 1024, 832, ctl);
    k_pack_rows_b<<<125, 256, 0, stream>>>(fc2_w, fc2wp, 1000, 1024, ctl);

    k_zero32<<<2653, 256, 0, stream>>>(x2p, 679168);

    // --- bn0 ---
    k_bn0_stats<<<dim3(32, 3), 256, 0, stream>>>(x, (double*)partS, ctl);
    k_bn0_fin<<<1, 64, 0, stream>>>((const double*)partS, bn0_g, bn0_b, bnp0, ctl);
    k_chk_f64<<<1, 256, 0, stream>>>((const double*)bnp0, 6, 0, ctl);

    // --- conv1 two-pass (f64) ---
    k_conv1_p1<<<dim3(83, 64, 4), 256, 0, stream>>>(x, bnp0, ws1, part1, ctl);
    k_fin1<<<1, 64, 0, stream>>>(part1, bn1_g, bn1_b, bnp1, ctl);
    k_chk_f64<<<1, 256, 0, stream>>>((const double*)bnp1, 128, 1, ctl);
    k_conv1_p2<<<dim3(83, 64, 4), 256, 0, stream>>>(x, bnp0, ws1, bnp1, x2p, ctl);

    // --- conv2 ---
    k_conv_bin<<<dim3(28, 64, 4), 256, 0, stream>>>((const uint2*)x2p, w2p, m2, 1742, 5306, 64);
    k_chk_u16<<<27864, 256, 0, stream>>>(m2, 7133184, 2624, 2, ctl);
    k_mstats<<<dim3(16, 64), 256, 0, stream>>>(m2, 1742, (u64*)partS);
    k_fin_m<<<1, 64, 0, stream>>>((const u64*)partS, 64.0 * 1742.0, bn2_g, bn2_b, pq2, ctl);
    k_chk_f64<<<1, 256, 0, stream>>>((const double*)pq2, 128, 3, ctl);
    k_pack_m<<<dim3(7, 64), 256, 0, stream>>>(m2, pq2, x3p, 1742);

    // --- conv3 ---
    k_conv_bin<<<dim3(9, 64, 4), 256, 0, stream>>>(x3p, w3p, m3, 554, 1742, 64);
    k_chk_u16<<<8864, 256, 0, stream>>>(m3, 2269184, 2624, 4, ctl);
    k_mstats<<<dim3(16, 64), 256, 0, stream>>>(m3, 554, (u64*)partS);
    k_fin_m<<<1, 64, 0, stream>>>((const u64*)partS, 64.0 * 554.0, bn3_g, bn3_b, pq3, ctl);
    k_chk_f64<<<1, 256, 0, stream>>>((const double*)pq3, 128, 5, ctl);
    k_pack_m<<<dim3(3, 64), 256, 0, stream>>>(m3, pq3, x4p, 554);

    // --- conv4 ---
    k_conv_bin<<<dim3(3, 64, 4), 256, 0, stream>>>(x4p, w4p, m4, 158, 554, 64);
    k_chk_u16<<<2528, 256, 0, stream>>>(m4, 647168, 2624, 6, ctl);
    k_mstats<<<dim3(16, 64), 256, 0, stream>>>(m4, 158, (u64*)partS);
    k_fin_m<<<1, 64, 0, stream>>>((const u64*)partS, 64.0 * 158.0, bn4_g, bn4_b, pq4, ctl);
    k_chk_f64<<<1, 256, 0, stream>>>((const double*)pq4, 128, 7, ctl);
    k_pack_m<<<dim3(1, 64), 256, 0, stream>>>(m4, pq4, x5p, 158);

    // --- conv5 ---
    k_conv_bin<<<dim3(1, 64, 2), 256, 0, stream>>>(x5p, w5p, m5, 26, 158, 32);
    k_chk_u16<<<208, 256, 0, stream>>>(m5, 53248, 2624, 8, ctl);
    k_pack_fc1in<<<26, 64, 0, stream>>>(m5, conv5_b, x6p, ctl);

    // --- fc1 ---
    k_fc_acc<<<dim3(4, 64), 256, 0, stream>>>(x6p, fc1wp, acc1, 1024, 26);
    k_chk_u16<<<256, 256, 0, stream>>>(acc1, 65536, 832, 9, ctl);
    k_fc_bn<<<4, 256, 0, stream>>>(acc1, 1024, bn5_g, bn5_b, pq5, ctl);
    k_chk_f64<<<8, 256, 0, stream>>>((const double*)pq5, 2048, 10, ctl);
    k_pack_fc2in<<<8, 256, 0, stream>>>(acc1, pq5, x7p);

    // --- fc2 ---
    k_fc_acc<<<dim3(4, 64), 256, 0, stream>>>(x7p, fc2wp, acc2, 1000, 32);
    k_chk_u16<<<250, 256, 0, stream>>>(acc2, 64000, 1024, 11, ctl);
    k_fc_bn<<<4, 256, 0, stream>>>(acc2, 1000, bn6_g, bn6_b, pq6, ctl);
    k_chk_f64<<<8, 256, 0, stream>>>((const double*)pq6, 2000, 12, ctl);

    // --- bn6 + log_softmax ---
    k_lsm<<<64, 256, 0, stream>>>(acc2, pq6, ctl, d_out);
}

// Round 4
// 1127.802 us; speedup vs baseline: 1.7617x; 1.7617x over previous
//
#include <hip/hip_runtime.h>
#include <hip/hip_bf16.h>
#include <stdint.h>

typedef __hip_bfloat16 bf16;
typedef unsigned long long u64;
typedef unsigned short u16;

static __device__ __forceinline__ float b2f(bf16 v) { return __bfloat162float(v); }

// dtype-flexible input read: f32 flag chosen at runtime by k_probe
static __device__ __forceinline__ float ldin(const void* p, long i, int f32) {
    return f32 ? ((const float*)p)[i] : __bfloat162float(((const bf16*)p)[i]);
}

// ---------------- control block: ctl[0]=diag, ctl[1]=f32 flag ----------------
__global__ void k_zero_ctl(unsigned* ctl) {
    if (threadIdx.x < 64) ctl[threadIdx.x] = 0u;
}

// probe input dtype: bf16-interpret even halves of x; sane -> bf16, garbage -> f32
__global__ void k_probe(const void* x, unsigned* ctl) {
    int tid = threadIdx.x;
    int good = 0;
    for (int i = tid; i < 1024; i += 256) {
        float v = __bfloat162float(((const bf16*)x)[2 * i]);
        float a = fabsf(v);
        if (v == 0.0f || (isfinite(v) && a >= 1e-4f && a <= 100.0f)) good++;
    }
    __shared__ int s[256];
    s[tid] = good; __syncthreads();
    for (int st = 128; st > 0; st >>= 1) {
        if (tid < st) s[tid] += s[tid + st];
        __syncthreads();
    }
    if (tid == 0) ctl[1] = (s[0] >= 700) ? 0u : 1u;   // sane bf16 -> 0, else f32 -> 1
}

__global__ void k_sentinel(void* outv, const unsigned* ctl, float val) {
    int i = blockIdx.x * 256 + threadIdx.x;
    if (i >= 64000) return;
    if (ctl[1]) ((float*)outv)[i] = val;
    else ((bf16*)outv)[i] = __float2bfloat16(val);
}

// ---------------- weight prep ----------------
__global__ void k_sign_w1(const void* w, float* ws, int n, const unsigned* ctl) {
    int f32 = ctl[1];
    int i = blockIdx.x * 256 + threadIdx.x;
    if (i < n) {
        float v = ldin(w, i, f32);
        ws[i] = (v > 0.f) ? 1.f : ((v < 0.f) ? -1.f : 0.f);
    }
}

__global__ void k_pack_convw(const void* w, uint2* wp, int Co, const unsigned* ctl) {
    int f32 = ctl[1];
    int t = blockIdx.x * 256 + threadIdx.x;
    if (t >= Co * 41) return;
    int co = t / 41, k = t % 41;
    unsigned w0 = 0, w1 = 0;
    for (int c = 0; c < 32; c++)
        if (ldin(w, (co * 64 + c) * 41 + k, f32) > 0.f) w0 |= (1u << c);
    for (int c = 0; c < 32; c++)
        if (ldin(w, (co * 64 + 32 + c) * 41 + k, f32) > 0.f) w1 |= (1u << c);
    wp[t] = make_uint2(w0, w1);
}

__global__ void k_pack_rows_b(const void* w, unsigned* wp, int rows, int F, const unsigned* ctl) {
    int f32 = ctl[1];
    int Fw = F >> 5;
    int t = blockIdx.x * 256 + threadIdx.x;
    if (t >= rows * Fw) return;
    int r = t / Fw, wi = t % Fw;
    unsigned m = 0;
    for (int j = 0; j < 32; j++)
        if (ldin(w, (long)r * F + wi * 32 + j, f32) > 0.f) m |= (1u << j);
    wp[t] = m;
}

// ---------------- bn0: f64 stats over x (N=64, C=3, L=16000) ----------------
__global__ void k_bn0_stats(const void* x, double* part, const unsigned* ctl) {
    int f32 = ctl[1];
    int c = blockIdx.y, s = blockIdx.x, tid = threadIdx.x;  // grid (32, 3)
    double s1 = 0, s2 = 0;
    for (int n = 0; n < 64; n++) {
        long base = (long)(n * 3 + c) * 16000;
        for (int l = s * 256 + tid; l < 16000; l += 32 * 256) {
            double v = (double)ldin(x, base + l, f32);
            s1 += v; s2 += v * v;
        }
    }
    __shared__ double a1[256], a2[256];
    a1[tid] = s1; a2[tid] = s2;
    __syncthreads();
    for (int st = 128; st > 0; st >>= 1) {
        if (tid < st) { a1[tid] += a1[tid + st]; a2[tid] += a2[tid + st]; }
        __syncthreads();
    }
    if (tid == 0) { part[(c * 32 + s) * 2] = a1[0]; part[(c * 32 + s) * 2 + 1] = a2[0]; }
}

__global__ void k_bn0_fin(const double* part, const void* g, const void* b, double2* bnp0,
                          const unsigned* ctl) {
    int f32 = ctl[1];
    int c = threadIdx.x;
    if (c >= 3) return;
    double s1 = 0, s2 = 0;
    for (int s = 0; s < 32; s++) { s1 += part[(c * 32 + s) * 2]; s2 += part[(c * 32 + s) * 2 + 1]; }
    double M = 64.0 * 16000.0;
    double mu = s1 / M, var = s2 / M - mu * mu;
    double A = (double)ldin(g, c, f32) / sqrt(var + 1e-5);
    bnp0[c] = make_double2(A, (double)ldin(b, c, f32) - mu * A);
}

// ---------------- conv1 (f64) ----------------
// Tile covers inputs [bx*192, bx*192+272); pooled pos lp = bx*64 + lane.
__device__ __forceinline__ void conv1_tile_load(const void* __restrict__ x,
                                                const double2* __restrict__ bnp0,
                                                int n, int base, int f32, double (*xt)[272]) {
    for (int i = threadIdx.x; i < 816; i += 256) {
        int c = i / 272, j = i % 272;
        int pos = base + j;
        double v = 0.0;
        if (pos < 16000) {
            double2 p = bnp0[c];
            v = (double)ldin(x, (long)(n * 3 + c) * 16000 + pos, f32) * p.x + p.y;
            v = fmin(fmax(v, -1.0), 1.0);   // hardtanh
        }
        xt[c][j] = v;
    }
}

// 8 output channels per wave: 9 LDS reads per (c,kc) chunk amortized over 96 FMAs.
// FMA ordering per output identical to round-3 (same c, kc, kk sequence) -> bit-identical y.
__device__ __forceinline__ void conv1_dot8(const double (*xt)[272], const float* __restrict__ ws,
                                           int lane, int co0, double yp[8]) {
    double acc[8][3] = {};
#pragma unroll 1
    for (int c = 0; c < 3; c++) {
#pragma unroll 1
        for (int kc = 0; kc < 40; kc += 4) {
            double xv[9];
#pragma unroll
            for (int i = 0; i < 9; i++) xv[i] = xt[c][3 * lane + 2 * kc + i];
#pragma unroll
            for (int kk = 0; kk < 4; kk++) {
#pragma unroll
                for (int j = 0; j < 8; j++) {
                    double wv = (double)ws[(co0 + j) * 123 + c * 41 + kc + kk];
                    acc[j][0] = fma(wv, xv[2 * kk], acc[j][0]);
                    acc[j][1] = fma(wv, xv[2 * kk + 1], acc[j][1]);
                    acc[j][2] = fma(wv, xv[2 * kk + 2], acc[j][2]);
                }
            }
        }
        double x0 = xt[c][3 * lane + 80], x1 = xt[c][3 * lane + 81], x2 = xt[c][3 * lane + 82];
#pragma unroll
        for (int j = 0; j < 8; j++) {
            double wv = (double)ws[(co0 + j) * 123 + c * 41 + 40];
            acc[j][0] = fma(wv, x0, acc[j][0]);
            acc[j][1] = fma(wv, x1, acc[j][1]);
            acc[j][2] = fma(wv, x2, acc[j][2]);
        }
    }
#pragma unroll
    for (int j = 0; j < 8; j++)
        yp[j] = fmax(fmax(acc[j][0], acc[j][1]), acc[j][2]);   // maxpool3 (bias cancels in bn1)
}

// ---- big-ws path: single pass, store pooled y (f64) ----
__global__ __launch_bounds__(256) void k_conv1_store(const void* __restrict__ x,
                                                     const double2* __restrict__ bnp0,
                                                     const float* __restrict__ ws,
                                                     double* __restrict__ y,
                                                     const unsigned* ctl) {
    __shared__ double xt[3][272];
    int f32 = ctl[1];
    int n = blockIdx.y, bx = blockIdx.x;
    conv1_tile_load(x, bnp0, n, bx * 192, f32, xt);
    __syncthreads();
    int lane = threadIdx.x & 63;
    int wave = __builtin_amdgcn_readfirstlane(threadIdx.x >> 6);
    int co0 = blockIdx.z * 32 + wave * 8;
    double yp[8];
    conv1_dot8(xt, ws, lane, co0, yp);
    int lp = bx * 64 + lane;
    if (lp < 5306) {
#pragma unroll
        for (int j = 0; j < 8; j++)
            y[((size_t)n * 64 + co0 + j) * 5306 + lp] = yp[j];
    }
}

// f64 per-channel stats of stored y: grid (16, 64)
__global__ void k_ystats(const double* __restrict__ y, double* __restrict__ part) {
    int c = blockIdx.y, s = blockIdx.x, tid = threadIdx.x;
    double s1 = 0, s2 = 0;
    for (int n = 0; n < 64; n++) {
        const double* p = y + ((size_t)(n * 64 + c)) * 5306;
        for (int l = s * 256 + tid; l < 5306; l += 16 * 256) {
            double v = p[l];
            s1 += v; s2 += v * v;
        }
    }
    __shared__ double a1[256], a2[256];
    a1[tid] = s1; a2[tid] = s2;
    __syncthreads();
    for (int st = 128; st > 0; st >>= 1) {
        if (tid < st) { a1[tid] += a1[tid + st]; a2[tid] += a2[tid + st]; }
        __syncthreads();
    }
    if (tid == 0) { part[(c * 16 + s) * 2] = a1[0]; part[(c * 16 + s) * 2 + 1] = a2[0]; }
}

__global__ void k_fin_y(const double* part, const void* g, const void* b, double2* bnp1,
                        const unsigned* ctl) {
    int f32 = ctl[1];
    int c = threadIdx.x;  // 64
    double s1 = 0, s2 = 0;
    for (int s = 0; s < 16; s++) { s1 += part[(c * 16 + s) * 2]; s2 += part[(c * 16 + s) * 2 + 1]; }
    double M = 64.0 * 5306.0;
    double mu = s1 / M, var = s2 / M - mu * mu;
    double A = (double)ldin(g, c, f32) / sqrt(var + 1e-5);
    bnp1[c] = make_double2(A, (double)ldin(b, c, f32) - mu * A);
}

// pack sign(y*A+B) over 64 channels -> uint2 per (n,l); grid (21, 64)
__global__ void k_pack_y(const double* __restrict__ y, const double2* __restrict__ bnp1,
                         uint2* __restrict__ xp) {
    int n = blockIdx.y;
    int l = blockIdx.x * 256 + threadIdx.x;
    if (l >= 5306) return;
    unsigned w0 = 0, w1 = 0;
    for (int c = 0; c < 32; c++) {
        double2 p = bnp1[c];
        if (y[((size_t)n * 64 + c) * 5306 + l] * p.x + p.y > 0.0) w0 |= 1u << c;
    }
    for (int c = 0; c < 32; c++) {
        double2 p = bnp1[c + 32];
        if (y[((size_t)n * 64 + c + 32) * 5306 + l] * p.x + p.y > 0.0) w1 |= 1u << c;
    }
    xp[(size_t)n * 5306 + l] = make_uint2(w0, w1);
}

// ---- fallback path: two-pass (no y buffer), 8-co waves ----
__global__ __launch_bounds__(256) void k_conv1_p1(const void* __restrict__ x,
                                                  const double2* __restrict__ bnp0,
                                                  const float* __restrict__ ws,
                                                  double* __restrict__ part1,
                                                  const unsigned* ctl) {
    __shared__ double xt[3][272];
    int f32 = ctl[1];
    int n = blockIdx.y, bx = blockIdx.x;
    conv1_tile_load(x, bnp0, n, bx * 192, f32, xt);
    __syncthreads();
    int lane = threadIdx.x & 63;
    int wave = __builtin_amdgcn_readfirstlane(threadIdx.x >> 6);
    int co0 = blockIdx.z * 32 + wave * 8;
    int lp = bx * 64 + lane;
    double yp[8];
    conv1_dot8(xt, ws, lane, co0, yp);
    bool ok = lp < 5306;
#pragma unroll
    for (int j = 0; j < 8; j++) {
        double s = ok ? yp[j] : 0.0;
        double q = ok ? yp[j] * yp[j] : 0.0;
        for (int off = 32; off > 0; off >>= 1) {
            s += __shfl_down(s, off, 64);
            q += __shfl_down(q, off, 64);
        }
        if (lane == 0) {
            int idx = (((co0 + j) * 83 + bx) * 64 + n) * 2;
            part1[idx] = s; part1[idx + 1] = q;
        }
    }
}

__global__ void k_fin1(const double* part1, const void* g, const void* b, double2* bnp1,
                       const unsigned* ctl) {
    int f32 = ctl[1];
    int c = threadIdx.x;  // 64
    double s = 0, q = 0;
    for (int bx = 0; bx < 83; bx++)
        for (int n = 0; n < 64; n++) {
            int idx = ((c * 83 + bx) * 64 + n) * 2;
            s += part1[idx]; q += part1[idx + 1];
        }
    double M = 64.0 * 5306.0;
    double mu = s / M, var = q / M - mu * mu;
    double A = (double)ldin(g, c, f32) / sqrt(var + 1e-5);
    bnp1[c] = make_double2(A, (double)ldin(b, c, f32) - mu * A);
}

__global__ __launch_bounds__(256) void k_conv1_p2(const void* __restrict__ x,
                                                  const double2* __restrict__ bnp0,
                                                  const float* __restrict__ ws,
                                                  const double2* __restrict__ bnp1,
                                                  unsigned* __restrict__ x2p,
                                                  const unsigned* ctl) {
    __shared__ double xt[3][272];
    __shared__ unsigned sl[4][64];
    int f32 = ctl[1];
    int n = blockIdx.y, bx = blockIdx.x;
    conv1_tile_load(x, bnp0, n, bx * 192, f32, xt);
    __syncthreads();
    int lane = threadIdx.x & 63;
    int wave = __builtin_amdgcn_readfirstlane(threadIdx.x >> 6);
    int co0 = blockIdx.z * 32 + wave * 8;
    double yp[8];
    conv1_dot8(xt, ws, lane, co0, yp);
    unsigned bits = 0;
#pragma unroll
    for (int j = 0; j < 8; j++) {
        double2 p = bnp1[co0 + j];
        if (yp[j] * p.x + p.y > 0.0) bits |= (1u << j);
    }
    sl[wave][lane] = bits;
    __syncthreads();
    if (threadIdx.x < 64) {
        int lp = bx * 64 + threadIdx.x;
        if (lp < 5306) {
            int l = threadIdx.x;
            unsigned word = sl[0][l] | (sl[1][l] << 8) | (sl[2][l] << 16) | (sl[3][l] << 24);
            x2p[(n * 5306 + lp) * 2 + blockIdx.z] = word;   // whole word owned -> direct store
        }
    }
}

// ---------------- binary conv (Ci=64) + fused maxpool3 -> pooled-min popcount ----------------
__global__ __launch_bounds__(256) void k_conv_bin(const uint2* __restrict__ xp,
                                                  const uint2* __restrict__ wp,
                                                  u16* __restrict__ mout,
                                                  int Lp, int Lin, int Co) {
    int n = blockIdx.y;
    int lane = threadIdx.x & 63, wave = threadIdx.x >> 6;
    int co0 = blockIdx.z * 16 + wave * 4;
    int base = blockIdx.x * 192;
    int lp = blockIdx.x * 64 + lane;

    __shared__ uint2 xt[272];
    for (int i = threadIdx.x; i < 272; i += 256) {
        int pos = base + i;
        xt[i] = (pos < Lin) ? xp[(size_t)n * Lin + pos] : make_uint2(0u, 0u);
    }
    __syncthreads();

    int acc[4][3] = {};
    for (int k = 0; k < 41; k++) {
        uint2 xa = xt[3 * lane + 2 * k];
        uint2 xb = xt[3 * lane + 2 * k + 1];
        uint2 xc = xt[3 * lane + 2 * k + 2];
#pragma unroll
        for (int j = 0; j < 4; j++) {
            uint2 w = wp[(co0 + j) * 41 + k];
            acc[j][0] += __popc(w.x ^ xa.x) + __popc(w.y ^ xa.y);
            acc[j][1] += __popc(w.x ^ xb.x) + __popc(w.y ^ xb.y);
            acc[j][2] += __popc(w.x ^ xc.x) + __popc(w.y ^ xc.y);
        }
    }
    if (lp < Lp) {
#pragma unroll
        for (int j = 0; j < 4; j++) {
            int m = min(min(acc[j][0], acc[j][1]), acc[j][2]);   // min m == max y
            mout[((size_t)n * Co + co0 + j) * Lp + lp] = (u16)m;
        }
    }
}

// ---------------- exact integer BN stats over m (u16) ----------------
__global__ void k_mstats(const u16* __restrict__ m, int L, u64* __restrict__ part) {
    int c = blockIdx.y, s = blockIdx.x, tid = threadIdx.x;  // grid (16, 64)
    u64 s1 = 0, s2 = 0;
    for (int n = 0; n < 64; n++) {
        const u16* p = m + ((size_t)(n * 64 + c)) * L;
        for (int l = s * 256 + tid; l < L; l += 16 * 256) {
            unsigned v = p[l];
            s1 += v; s2 += (u64)v * v;
        }
    }
    __shared__ u64 a1[256], a2[256];
    a1[tid] = s1; a2[tid] = s2;
    __syncthreads();
    for (int st = 128; st > 0; st >>= 1) {
        if (tid < st) { a1[tid] += a1[tid + st]; a2[tid] += a2[tid + st]; }
        __syncthreads();
    }
    if (tid == 0) { part[(c * 16 + s) * 2] = a1[0]; part[(c * 16 + s) * 2 + 1] = a2[0]; }
}

// y = K - 2m + bias; v = m*p + q; p = -2A, q = 2A*mu + beta; var_y = 4 var_m
__global__ void k_fin_m(const u64* part, double M, const void* g, const void* b, double2* pq,
                        const unsigned* ctl) {
    int f32 = ctl[1];
    int c = threadIdx.x;  // 64
    u64 s1 = 0, s2 = 0;
    for (int s = 0; s < 16; s++) { s1 += part[(c * 16 + s) * 2]; s2 += part[(c * 16 + s) * 2 + 1]; }
    double mu = (double)s1 / M;
    double varm = (double)s2 / M - mu * mu;
    double A = (double)ldin(g, c, f32) / sqrt(4.0 * varm + 1e-5);
    pq[c] = make_double2(-2.0 * A, 2.0 * A * mu + (double)ldin(b, c, f32));
}

__global__ void k_pack_m(const u16* __restrict__ m, const double2* __restrict__ pq,
                         uint2* __restrict__ xp, int L) {
    int n = blockIdx.y;
    int l = blockIdx.x * 256 + threadIdx.x;
    if (l >= L) return;
    unsigned w0 = 0, w1 = 0;
    for (int c = 0; c < 32; c++) {
        double2 p = pq[c];
        if ((double)m[((size_t)n * 64 + c) * L + l] * p.x + p.y > 0.0) w0 |= 1u << c;
    }
    for (int c = 0; c < 32; c++) {
        double2 p = pq[c + 32];
        if ((double)m[((size_t)n * 64 + c + 32) * L + l] * p.x + p.y > 0.0) w1 |= 1u << c;
    }
    xp[(size_t)n * L + l] = make_uint2(w0, w1);
}

// fc1 input: sign(2624 - 2*m5 + conv5_b), flatten (32,26)->832
__global__ void k_pack_fc1in(const u16* __restrict__ m5, const void* __restrict__ b5,
                             unsigned* __restrict__ x6p, const unsigned* ctl) {
    int f32 = ctl[1];
    int t = blockIdx.x * 64 + threadIdx.x;  // 26 x 64
    if (t >= 64 * 26) return;
    int n = t / 26, wi = t % 26;
    unsigned mask = 0;
    for (int j = 0; j < 32; j++) {
        int f = wi * 32 + j, c = f / 26, l = f % 26;
        double y = 2624.0 - 2.0 * (double)m5[(n * 32 + c) * 26 + l] + (double)ldin(b5, c, f32);
        if (y > 0.0) mask |= 1u << j;
    }
    x6p[n * 26 + wi] = mask;
}

__global__ void k_fc_acc(const unsigned* __restrict__ xp, const unsigned* __restrict__ wp,
                         u16* __restrict__ acc, int J, int W) {
    int n = blockIdx.y;
    int j = blockIdx.x * 256 + threadIdx.x;
    if (j >= J) return;
    unsigned a = 0;
    for (int w = 0; w < W; w++) a += __popc(xp[n * W + w] ^ wp[j * W + w]);
    acc[n * J + j] = (u16)a;
}

__global__ void k_fc_bn(const u16* __restrict__ acc, int J, const void* g, const void* b,
                        double2* __restrict__ pq, const unsigned* ctl) {
    int f32 = ctl[1];
    int j = blockIdx.x * 256 + threadIdx.x;
    if (j >= J) return;
    u64 s1 = 0, s2 = 0;
    for (int n = 0; n < 64; n++) { unsigned a = acc[n * J + j]; s1 += a; s2 += (u64)a * a; }
    double mu = (double)s1 / 64.0;
    double varm = (double)s2 / 64.0 - mu * mu;
    double A = (double)ldin(g, j, f32) / sqrt(4.0 * varm + 1e-5);
    pq[j] = make_double2(-2.0 * A, 2.0 * A * mu + (double)ldin(b, j, f32));
}

__global__ void k_pack_fc2in(const u16* __restrict__ acc1, const double2* __restrict__ pq5,
                             unsigned* __restrict__ x7p) {
    int t = blockIdx.x * 256 + threadIdx.x;  // 8 x 256 = 2048
    if (t >= 64 * 32) return;
    int n = t / 32, wi = t % 32;
    unsigned mask = 0;
    for (int j = 0; j < 32; j++) {
        int f = wi * 32 + j;
        double2 p = pq5[f];
        if ((double)acc1[n * 1024 + f] * p.x + p.y > 0.0) mask |= 1u << j;
    }
    x7p[t] = mask;
}

// bn6 + log_softmax; diag sentinel + non-finite sanitize; dtype per flag
__global__ void k_lsm(const u16* __restrict__ acc2, const double2* __restrict__ pq6,
                      const unsigned* ctl, void* outv) {
    int n = blockIdx.x, tid = threadIdx.x;
    int f32 = ctl[1];
    unsigned dg = ctl[0];
    if (dg) {
        int k = __ffs(dg) - 1;
        float sv = -(300.0f + 20.0f * (float)k);
#pragma unroll
        for (int i = 0; i < 4; i++) {
            int j = tid + i * 256;
            if (j < 1000) {
                if (f32) ((float*)outv)[n * 1000 + j] = sv;
                else ((bf16*)outv)[n * 1000 + j] = __float2bfloat16(sv);
            }
        }
        return;
    }
    __shared__ double red[256];
    double v[4];
    double mx = -1e300;
#pragma unroll
    for (int i = 0; i < 4; i++) {
        int j = tid + i * 256;
        if (j < 1000) {
            double2 p = pq6[j];
            v[i] = (double)acc2[n * 1000 + j] * p.x + p.y;
            mx = fmax(mx, v[i]);
        } else v[i] = -1e300;
    }
    red[tid] = mx; __syncthreads();
    for (int s = 128; s > 0; s >>= 1) {
        if (tid < s) red[tid] = fmax(red[tid], red[tid + s]);
        __syncthreads();
    }
    mx = red[0]; __syncthreads();
    double sum = 0.0;
#pragma unroll
    for (int i = 0; i < 4; i++) {
        int j = tid + i * 256;
        if (j < 1000) sum += exp(v[i] - mx);
    }
    red[tid] = sum; __syncthreads();
    for (int s = 128; s > 0; s >>= 1) {
        if (tid < s) red[tid] += red[tid + s];
        __syncthreads();
    }
    double ls = log(red[0]);
#pragma unroll
    for (int i = 0; i < 4; i++) {
        int j = tid + i * 256;
        if (j < 1000) {
            float r = (float)(v[i] - mx - ls);
            if (!isfinite(r)) r = -700.0f;
            if (f32) ((float*)outv)[n * 1000 + j] = r;
            else ((bf16*)outv)[n * 1000 + j] = __float2bfloat16(r);
        }
    }
}

extern "C" void kernel_launch(void* const* d_in, const int* in_sizes, int n_in,
                              void* d_out, int out_size, void* d_ws, size_t ws_size,
                              hipStream_t stream) {
    const void* x       = d_in[0];
    const void* bn0_g   = d_in[1];
    const void* bn0_b   = d_in[2];
    const void* conv1_w = d_in[3];
    const void* bn1_g   = d_in[5];
    const void* bn1_b   = d_in[6];
    const void* conv2_w = d_in[7];
    const void* bn2_g   = d_in[9];
    const void* bn2_b   = d_in[10];
    const void* conv3_w = d_in[11];
    const void* bn3_g   = d_in[13];
    const void* bn3_b   = d_in[14];
    const void* conv4_w = d_in[15];
    const void* bn4_g   = d_in[17];
    const void* bn4_b   = d_in[18];
    const void* conv5_w = d_in[19];
    const void* conv5_b = d_in[20];
    const void* fc1_w   = d_in[21];
    const void* bn5_g   = d_in[23];
    const void* bn5_b   = d_in[24];
    const void* fc2_w   = d_in[25];
    const void* bn6_g   = d_in[27];
    const void* bn6_b   = d_in[28];

    char* wsb = (char*)d_ws;
    size_t off = 0;
    auto alloc = [&](size_t bytes) -> void* {
        off = (off + 255) & ~(size_t)255;
        void* p = wsb + off;
        off += bytes;
        return p;
    };

    unsigned* ctl   = (unsigned*)alloc(256);           // [0]=diag, [1]=f32 flag
    unsigned* x2p   = (unsigned*)alloc(2716672);       // 5306*64 uint2
    double*   part1 = (double*)alloc(5439488);         // fallback stats partials
    u16*      m2    = (u16*)alloc(14270464);           // 64*64*1742
    uint2*    x3p   = (uint2*)alloc(891904);
    u16*      m3    = (u16*)alloc(4538368);            // 64*64*554
    uint2*    x4p   = (uint2*)alloc(283648);
    u16*      m4    = (u16*)alloc(1294336);            // 64*64*158
    uint2*    x5p   = (uint2*)alloc(80896);
    u16*      m5    = (u16*)alloc(106496);             // 64*32*26
    unsigned* x6p   = (unsigned*)alloc(6656);
    u16*      acc1  = (u16*)alloc(131072);             // 64*1024
    unsigned* x7p   = (unsigned*)alloc(8192);
    u16*      acc2  = (u16*)alloc(128000);             // 64*1000
    float*    ws1   = (float*)alloc(31488);
    uint2*    w2p   = (uint2*)alloc(20992);
    uint2*    w3p   = (uint2*)alloc(20992);
    uint2*    w4p   = (uint2*)alloc(20992);
    uint2*    w5p   = (uint2*)alloc(10496);
    unsigned* fc1wp = (unsigned*)alloc(106496);
    unsigned* fc2wp = (unsigned*)alloc(128000);
    void*     partS = alloc(32768);                    // shared stats scratch
    double2*  bnp0  = (double2*)alloc(3 * 16);
    double2*  bnp1  = (double2*)alloc(64 * 16);
    double2*  pq2   = (double2*)alloc(64 * 16);
    double2*  pq3   = (double2*)alloc(64 * 16);
    double2*  pq4   = (double2*)alloc(64 * 16);
    double2*  pq5   = (double2*)alloc(1024 * 16);
    double2*  pq6   = (double2*)alloc(1000 * 16);
    size_t need_small = (off + 255) & ~(size_t)255;
    double*   y64   = (double*)alloc(173867008);       // 64*64*5306 f64 pooled conv1 out
    size_t need_big = (off + 255) & ~(size_t)255;

    k_zero_ctl<<<1, 64, 0, stream>>>(ctl);
    k_probe<<<1, 256, 0, stream>>>(x, ctl);

    if (n_in != 29) {
        k_sentinel<<<250, 256, 0, stream>>>(d_out, ctl, -(3000.0f + (float)n_in));
        return;
    }
    if (ws_size < need_small) {
        k_sentinel<<<250, 256, 0, stream>>>(d_out, ctl, -1500.0f);
        return;
    }
    const bool big = (ws_size >= need_big);   // host-side constant -> capture-stable

    // --- weight prep ---
    k_sign_w1<<<31, 256, 0, stream>>>(conv1_w, ws1, 7872, ctl);
    k_pack_convw<<<11, 256, 0, stream>>>(conv2_w, w2p, 64, ctl);
    k_pack_convw<<<11, 256, 0, stream>>>(conv3_w, w3p, 64, ctl);
    k_pack_convw<<<11, 256, 0, stream>>>(conv4_w, w4p, 64, ctl);
    k_pack_convw<<<6, 256, 0, stream>>>(conv5_w, w5p, 32, ctl);
    k_pack_rows_b<<<104, 256, 0, stream>>>(fc1_w, fc1wp, 1024, 832, ctl);
    k_pack_rows_b<<<125, 256, 0, stream>>>(fc2_w, fc2wp, 1000, 1024, ctl);

    // --- bn0 ---
    k_bn0_stats<<<dim3(32, 3), 256, 0, stream>>>(x, (double*)partS, ctl);
    k_bn0_fin<<<1, 64, 0, stream>>>((const double*)partS, bn0_g, bn0_b, bnp0, ctl);

    // --- conv1 (f64) -> bn1 -> x2p ---
    if (big) {
        k_conv1_store<<<dim3(83, 64, 2), 256, 0, stream>>>(x, bnp0, ws1, y64, ctl);
        k_ystats<<<dim3(16, 64), 256, 0, stream>>>(y64, (double*)partS);
        k_fin_y<<<1, 64, 0, stream>>>((const double*)partS, bn1_g, bn1_b, bnp1, ctl);
        k_pack_y<<<dim3(21, 64), 256, 0, stream>>>(y64, bnp1, (uint2*)x2p);
    } else {
        k_conv1_p1<<<dim3(83, 64, 2), 256, 0, stream>>>(x, bnp0, ws1, part1, ctl);
        k_fin1<<<1, 64, 0, stream>>>(part1, bn1_g, bn1_b, bnp1, ctl);
        k_conv1_p2<<<dim3(83, 64, 2), 256, 0, stream>>>(x, bnp0, ws1, bnp1, x2p, ctl);
    }

    // --- conv2 -> m2 -> bn2 -> x3p ---
    k_conv_bin<<<dim3(28, 64, 4), 256, 0, stream>>>((const uint2*)x2p, w2p, m2, 1742, 5306, 64);
    k_mstats<<<dim3(16, 64), 256, 0, stream>>>(m2, 1742, (u64*)partS);
    k_fin_m<<<1, 64, 0, stream>>>((const u64*)partS, 64.0 * 1742.0, bn2_g, bn2_b, pq2, ctl);
    k_pack_m<<<dim3(7, 64), 256, 0, stream>>>(m2, pq2, x3p, 1742);

    // --- conv3 -> m3 -> bn3 -> x4p ---
    k_conv_bin<<<dim3(9, 64, 4), 256, 0, stream>>>(x3p, w3p, m3, 554, 1742, 64);
    k_mstats<<<dim3(16, 64), 256, 0, stream>>>(m3, 554, (u64*)partS);
    k_fin_m<<<1, 64, 0, stream>>>((const u64*)partS, 64.0 * 554.0, bn3_g, bn3_b, pq3, ctl);
    k_pack_m<<<dim3(3, 64), 256, 0, stream>>>(m3, pq3, x4p, 554);

    // --- conv4 -> m4 -> bn4 -> x5p ---
    k_conv_bin<<<dim3(3, 64, 4), 256, 0, stream>>>(x4p, w4p, m4, 158, 554, 64);
    k_mstats<<<dim3(16, 64), 256, 0, stream>>>(m4, 158, (u64*)partS);
    k_fin_m<<<1, 64, 0, stream>>>((const u64*)partS, 64.0 * 158.0, bn4_g, bn4_b, pq4, ctl);
    k_pack_m<<<dim3(1, 64), 256, 0, stream>>>(m4, pq4, x5p, 158);

    // --- conv5 -> m5 -> fc1 input ---
    k_conv_bin<<<dim3(1, 64, 2), 256, 0, stream>>>(x5p, w5p, m5, 26, 158, 32);
    k_pack_fc1in<<<26, 64, 0, stream>>>(m5, conv5_b, x6p, ctl);

    // --- fc1 -> bn5 -> fc2 input ---
    k_fc_acc<<<dim3(4, 64), 256, 0, stream>>>(x6p, fc1wp, acc1, 1024, 26);
    k_fc_bn<<<4, 256, 0, stream>>>(acc1, 1024, bn5_g, bn5_b, pq5, ctl);
    k_pack_fc2in<<<8, 256, 0, stream>>>(acc1, pq5, x7p);

    // --- fc2 -> bn6 -> log_softmax ---
    k_fc_acc<<<dim3(4, 64), 256, 0, stream>>>(x7p, fc2wp, acc2, 1000, 32);
    k_fc_bn<<<4, 256, 0, stream>>>(acc2, 1000, bn6_g, bn6_b, pq6, ctl);
    k_lsm<<<64, 256, 0, stream>>>(acc2, pq6, ctl, d_out);
}

// Round 5
// 923.396 us; speedup vs baseline: 2.1516x; 1.2214x over previous
//
#include <hip/hip_runtime.h>
#include <hip/hip_bf16.h>
#include <stdint.h>

typedef __hip_bfloat16 bf16;
typedef unsigned long long u64;
typedef unsigned short u16;

static __device__ __forceinline__ float b2f(bf16 v) { return __bfloat162float(v); }
static __device__ __forceinline__ float ldin(const void* p, long i, int f32) {
    return f32 ? ((const float*)p)[i] : __bfloat162float(((const bf16*)p)[i]);
}

// ---------------- probe: ctl[0]=0 (diag unused), ctl[1]=f32 flag ----------------
__global__ void k_probe(const void* x, unsigned* ctl) {
    int tid = threadIdx.x;
    int good = 0;
    for (int i = tid; i < 1024; i += 256) {
        float v = __bfloat162float(((const bf16*)x)[2 * i]);
        float a = fabsf(v);
        if (v == 0.0f || (isfinite(v) && a >= 1e-4f && a <= 100.0f)) good++;
    }
    __shared__ int s[256];
    s[tid] = good; __syncthreads();
    for (int st = 128; st > 0; st >>= 1) {
        if (tid < st) s[tid] += s[tid + st];
        __syncthreads();
    }
    if (tid == 0) { ctl[0] = 0u; ctl[1] = (s[0] >= 700) ? 0u : 1u; }
}

__global__ void k_sentinel(void* outv, const unsigned* ctl, float val) {
    int i = blockIdx.x * 256 + threadIdx.x;
    if (i >= 64000) return;
    if (ctl[1]) ((float*)outv)[i] = val;
    else ((bf16*)outv)[i] = __float2bfloat16(val);
}

// ---------------- mega prep: weights + zero stat scratch ----------------
__device__ __forceinline__ void pack_convw_task(const void* w, uint2* wp, int Co, int f32,
                                                int bx, int tid) {
    int t = bx * 256 + tid;
    if (t >= Co * 41) return;
    int co = t / 41, k = t % 41;
    unsigned w0 = 0, w1 = 0;
    for (int c = 0; c < 32; c++)
        if (ldin(w, (co * 64 + c) * 41 + k, f32) > 0.f) w0 |= (1u << c);
    for (int c = 0; c < 32; c++)
        if (ldin(w, (co * 64 + 32 + c) * 41 + k, f32) > 0.f) w1 |= (1u << c);
    wp[t] = make_uint2(w0, w1);
}
__device__ __forceinline__ void pack_rows_task(const void* w, unsigned* wp, int rows, int F,
                                               int f32, int bx, int tid) {
    int Fw = F >> 5;
    int t = bx * 256 + tid;
    if (t >= rows * Fw) return;
    int r = t / Fw, wi = t % Fw;
    unsigned m = 0;
    for (int j = 0; j < 32; j++)
        if (ldin(w, (long)r * F + wi * 32 + j, f32) > 0.f) m |= (1u << j);
    wp[t] = m;
}

__global__ void k_prep(const void* c1w, const void* c2w, const void* c3w, const void* c4w,
                       const void* c5w, const void* f1w, const void* f2w,
                       double* ws1d, uint2* w2p, uint2* w3p, uint2* w4p, uint2* w5p,
                       unsigned* fc1wp, unsigned* fc2wp, u64* stats, const unsigned* ctl) {
    int f32 = ctl[1];
    int task = blockIdx.y, bx = blockIdx.x, tid = threadIdx.x;
    switch (task) {
        case 0: {
            int i = bx * 256 + tid;
            if (i < 7872) {
                float v = ldin(c1w, i, f32);
                ws1d[i] = (v > 0.f) ? 1.0 : ((v < 0.f) ? -1.0 : 0.0);
            }
        } break;
        case 1: pack_convw_task(c2w, w2p, 64, f32, bx, tid); break;
        case 2: pack_convw_task(c3w, w3p, 64, f32, bx, tid); break;
        case 3: pack_convw_task(c4w, w4p, 64, f32, bx, tid); break;
        case 4: pack_convw_task(c5w, w5p, 32, f32, bx, tid); break;
        case 5: pack_rows_task(f1w, fc1wp, 1024, 832, f32, bx, tid); break;
        case 6: pack_rows_task(f2w, fc2wp, 1000, 1024, f32, bx, tid); break;
        case 7: {
            int i = bx * 256 + tid;
            if (i < 12288) stats[i] = 0ull;
        } break;
    }
}

// ---------------- bn0 stats ----------------
__global__ void k_bn0_stats(const void* x, double* part, const unsigned* ctl) {
    int f32 = ctl[1];
    int c = blockIdx.y, s = blockIdx.x, tid = threadIdx.x;  // grid (32, 3)
    double s1 = 0, s2 = 0;
    for (int n = 0; n < 64; n++) {
        long base = (long)(n * 3 + c) * 16000;
        for (int l = s * 256 + tid; l < 16000; l += 32 * 256) {
            double v = (double)ldin(x, base + l, f32);
            s1 += v; s2 += v * v;
        }
    }
    __shared__ double a1[256], a2[256];
    a1[tid] = s1; a2[tid] = s2;
    __syncthreads();
    for (int st = 128; st > 0; st >>= 1) {
        if (tid < st) { a1[tid] += a1[tid + st]; a2[tid] += a2[tid + st]; }
        __syncthreads();
    }
    if (tid == 0) { part[(c * 32 + s) * 2] = a1[0]; part[(c * 32 + s) * 2 + 1] = a2[0]; }
}

// ---------------- conv1: single pass, 16 co/wave, fused bn0-fin + bn1-partials ----------------
// grid (83, 64); pooled lp = bx*64+lane; tile covers [bx*192, bx*192+272)
__global__ __launch_bounds__(256) void k_conv1_store(const void* __restrict__ x,
                                                     const double* __restrict__ part0,
                                                     const void* __restrict__ g0,
                                                     const void* __restrict__ b0,
                                                     const double* __restrict__ wsd,
                                                     double* __restrict__ y,
                                                     double* __restrict__ part1,
                                                     const unsigned* __restrict__ ctl) {
    __shared__ double xt[3][272];
    __shared__ double2 b0s[3];
    int f32 = ctl[1];
    int n = blockIdx.y, bx = blockIdx.x, tid = threadIdx.x;
    // fold bn0 finalize (order matches prior rounds: s = 0..31)
    if (tid < 3) {
        int c = tid;
        double s1 = 0, s2 = 0;
        for (int s = 0; s < 32; s++) { s1 += part0[(c * 32 + s) * 2]; s2 += part0[(c * 32 + s) * 2 + 1]; }
        double M = 64.0 * 16000.0;
        double mu = s1 / M, var = s2 / M - mu * mu;
        double A = (double)ldin(g0, c, f32) / sqrt(var + 1e-5);
        b0s[c] = make_double2(A, (double)ldin(b0, c, f32) - mu * A);
    }
    __syncthreads();
    int base = bx * 192;
    for (int i = tid; i < 816; i += 256) {
        int c = i / 272, j = i % 272;
        int pos = base + j;
        double v = 0.0;
        if (pos < 16000) {
            double2 p = b0s[c];
            v = (double)ldin(x, (long)(n * 3 + c) * 16000 + pos, f32) * p.x + p.y;
            v = fmin(fmax(v, -1.0), 1.0);
        }
        xt[c][j] = v;
    }
    __syncthreads();

    int lane = tid & 63;
    int wave = __builtin_amdgcn_readfirstlane(tid >> 6);
    int co0 = wave * 16;

    double acc[16][3] = {};
#pragma unroll 1
    for (int c = 0; c < 3; c++) {
        double carry = xt[c][3 * lane];
#pragma unroll 1
        for (int kc = 0; kc < 40; kc += 4) {
            double xv[9];
            xv[0] = carry;
#pragma unroll
            for (int i = 1; i < 9; i++) xv[i] = xt[c][3 * lane + 2 * kc + i];
            carry = xv[8];
#pragma unroll
            for (int kk = 0; kk < 4; kk++) {
#pragma unroll
                for (int j = 0; j < 16; j++) {
                    double wv = wsd[(co0 + j) * 123 + c * 41 + kc + kk];
                    acc[j][0] = fma(wv, xv[2 * kk], acc[j][0]);
                    acc[j][1] = fma(wv, xv[2 * kk + 1], acc[j][1]);
                    acc[j][2] = fma(wv, xv[2 * kk + 2], acc[j][2]);
                }
            }
        }
        double x0 = carry, x1 = xt[c][3 * lane + 81], x2 = xt[c][3 * lane + 82];
#pragma unroll
        for (int j = 0; j < 16; j++) {
            double wv = wsd[(co0 + j) * 123 + c * 41 + 40];
            acc[j][0] = fma(wv, x0, acc[j][0]);
            acc[j][1] = fma(wv, x1, acc[j][1]);
            acc[j][2] = fma(wv, x2, acc[j][2]);
        }
    }

    int lp = bx * 64 + lane;
    bool ok = lp < 5306;
#pragma unroll
    for (int j = 0; j < 16; j++) {
        double yp = fmax(fmax(acc[j][0], acc[j][1]), acc[j][2]);   // maxpool3 (bias cancels in bn1)
        if (ok) y[((size_t)n * 64 + co0 + j) * 5306 + lp] = yp;
        double s = ok ? yp : 0.0;
        double q = ok ? yp * yp : 0.0;
        for (int off = 32; off > 0; off >>= 1) {
            s += __shfl_down(s, off, 64);
            q += __shfl_down(q, off, 64);
        }
        if (lane == 0) {
            size_t idx = ((size_t)(co0 + j) * 5312 + (size_t)bx * 64 + n) * 2;
            part1[idx] = s; part1[idx + 1] = q;
        }
    }
}

// bn1 finalize: grid 64 blocks, one per channel
__global__ void k_fin_y(const double* __restrict__ part1, const void* g, const void* b,
                        double2* __restrict__ bnp1, const unsigned* ctl) {
    int f32 = ctl[1];
    int c = blockIdx.x, tid = threadIdx.x;
    double s1 = 0, s2 = 0;
    for (int i = tid; i < 5312; i += 256) {
        s1 += part1[((size_t)c * 5312 + i) * 2];
        s2 += part1[((size_t)c * 5312 + i) * 2 + 1];
    }
    __shared__ double a1[256], a2[256];
    a1[tid] = s1; a2[tid] = s2;
    __syncthreads();
    for (int st = 128; st > 0; st >>= 1) {
        if (tid < st) { a1[tid] += a1[tid + st]; a2[tid] += a2[tid + st]; }
        __syncthreads();
    }
    if (tid == 0) {
        double M = 64.0 * 5306.0;
        double mu = a1[0] / M, var = a2[0] / M - mu * mu;
        double A = (double)ldin(g, c, f32) / sqrt(var + 1e-5);
        bnp1[c] = make_double2(A, (double)ldin(b, c, f32) - mu * A);
    }
}

// pack sign(y*A+B) -> uint2 per (n,l); grid (21, 64)
__global__ void k_pack_y(const double* __restrict__ y, const double2* __restrict__ bnp1,
                         uint2* __restrict__ xp) {
    int n = blockIdx.y;
    int l = blockIdx.x * 256 + threadIdx.x;
    if (l >= 5306) return;
    unsigned w0 = 0, w1 = 0;
    for (int c = 0; c < 32; c++) {
        double2 p = bnp1[c];
        if (y[((size_t)n * 64 + c) * 5306 + l] * p.x + p.y > 0.0) w0 |= 1u << c;
    }
    for (int c = 0; c < 32; c++) {
        double2 p = bnp1[c + 32];
        if (y[((size_t)n * 64 + c + 32) * 5306 + l] * p.x + p.y > 0.0) w1 |= 1u << c;
    }
    xp[(size_t)n * 5306 + l] = make_uint2(w0, w1);
}

// ---------------- binary conv: 8 co/wave, rolling window, fused integer stats ----------------
// grid (ceil(Lp/64), 64, Co/32); stat: u64[(c*16+ (bx&15))*2] accumulators or nullptr
__global__ __launch_bounds__(256) void k_conv_bin(const uint2* __restrict__ xp,
                                                  const uint2* __restrict__ wp,
                                                  u16* __restrict__ mout,
                                                  int Lp, int Lin, int Co,
                                                  u64* __restrict__ stat) {
    int n = blockIdx.y, tid = threadIdx.x;
    int lane = tid & 63;
    int wave = __builtin_amdgcn_readfirstlane(tid >> 6);
    int co0 = blockIdx.z * 32 + wave * 8;
    int base = blockIdx.x * 192;
    int lp = blockIdx.x * 64 + lane;

    __shared__ uint2 xt[272];
    for (int i = tid; i < 272; i += 256) {
        int pos = base + i;
        xt[i] = (pos < Lin) ? xp[(size_t)n * Lin + pos] : make_uint2(0u, 0u);
    }
    __syncthreads();

    int acc[8][3] = {};
    uint2 xa = xt[3 * lane];
    for (int k = 0; k < 41; k++) {
        uint2 xb = xt[3 * lane + 2 * k + 1];
        uint2 xc = xt[3 * lane + 2 * k + 2];
#pragma unroll
        for (int j = 0; j < 8; j++) {
            uint2 w = wp[(co0 + j) * 41 + k];
            acc[j][0] += __popc(w.x ^ xa.x) + __popc(w.y ^ xa.y);
            acc[j][1] += __popc(w.x ^ xb.x) + __popc(w.y ^ xb.y);
            acc[j][2] += __popc(w.x ^ xc.x) + __popc(w.y ^ xc.y);
        }
        xa = xc;
    }
    bool ok = lp < Lp;
    int sb = blockIdx.x & 15;
#pragma unroll
    for (int j = 0; j < 8; j++) {
        int m = min(min(acc[j][0], acc[j][1]), acc[j][2]);
        if (ok) mout[((size_t)n * Co + co0 + j) * Lp + lp] = (u16)m;
        if (stat) {
            unsigned s = ok ? (unsigned)m : 0u;
            unsigned q = ok ? (unsigned)(m * m) : 0u;
            for (int off = 32; off > 0; off >>= 1) {
                s += __shfl_down(s, off, 64);
                q += __shfl_down(q, off, 64);
            }
            if (lane == 0) {
                atomicAdd(&stat[((co0 + j) * 16 + sb) * 2], (u64)s);
                atomicAdd(&stat[((co0 + j) * 16 + sb) * 2 + 1], (u64)q);
            }
        }
    }
}

// pack sign(m*p+q), folding BN finalize from u64 stats
__global__ void k_pack_m(const u16* __restrict__ m, const u64* __restrict__ stat,
                         const void* g, const void* b, uint2* __restrict__ xp,
                         int L, double M, const unsigned* ctl) {
    __shared__ double2 pqs[64];
    int f32 = ctl[1];
    int tid = threadIdx.x;
    if (tid < 64) {
        int c = tid;
        u64 s1 = 0, s2 = 0;
        for (int s = 0; s < 16; s++) { s1 += stat[(c * 16 + s) * 2]; s2 += stat[(c * 16 + s) * 2 + 1]; }
        double mu = (double)s1 / M;
        double varm = (double)s2 / M - mu * mu;
        double A = (double)ldin(g, c, f32) / sqrt(4.0 * varm + 1e-5);
        pqs[c] = make_double2(-2.0 * A, 2.0 * A * mu + (double)ldin(b, c, f32));
    }
    __syncthreads();
    int n = blockIdx.y;
    int l = blockIdx.x * 256 + tid;
    if (l >= L) return;
    unsigned w0 = 0, w1 = 0;
    for (int c = 0; c < 32; c++) {
        double2 p = pqs[c];
        if ((double)m[((size_t)n * 64 + c) * L + l] * p.x + p.y > 0.0) w0 |= 1u << c;
    }
    for (int c = 0; c < 32; c++) {
        double2 p = pqs[c + 32];
        if ((double)m[((size_t)n * 64 + c + 32) * L + l] * p.x + p.y > 0.0) w1 |= 1u << c;
    }
    xp[(size_t)n * L + l] = make_uint2(w0, w1);
}

// ---------------- fc tail ----------------
// fc1: build x6p[n] in LDS from m5 + conv5_b, popcount vs fc1 weights, u64 stats
__global__ void k_fc1(const u16* __restrict__ m5, const void* __restrict__ b5,
                      const unsigned* __restrict__ fc1wp, u16* __restrict__ acc1,
                      u64* __restrict__ s5, const unsigned* ctl) {
    __shared__ unsigned xw[26];
    int f32 = ctl[1];
    int n = blockIdx.y, tid = threadIdx.x;
    if (tid < 26) {
        unsigned mask = 0;
        for (int j = 0; j < 32; j++) {
            int f = tid * 32 + j, c = f / 26, l = f % 26;
            double yv = 2624.0 - 2.0 * (double)m5[(n * 32 + c) * 26 + l] + (double)ldin(b5, c, f32);
            if (yv > 0.0) mask |= 1u << j;
        }
        xw[tid] = mask;
    }
    __syncthreads();
    int j = blockIdx.x * 256 + tid;   // grid x=4 -> j<1024
    unsigned a = 0;
    for (int w = 0; w < 26; w++) a += __popc(xw[w] ^ fc1wp[j * 26 + w]);
    acc1[n * 1024 + j] = (u16)a;
    atomicAdd(&s5[j * 2], (u64)a);
    atomicAdd(&s5[j * 2 + 1], (u64)(a * a));
}

// fc2: fold bn5 finalize, pack x7p[n] in LDS, popcount vs fc2 weights, u64 stats
__global__ void k_fc2(const u16* __restrict__ acc1, const u64* __restrict__ s5,
                      const void* g5, const void* b5, const unsigned* __restrict__ fc2wp,
                      u16* __restrict__ acc2, u64* __restrict__ s6, const unsigned* ctl) {
    __shared__ double2 pq5s[1024];
    __shared__ unsigned xw[32];
    int f32 = ctl[1];
    int n = blockIdx.y, tid = threadIdx.x;
    for (int f = tid; f < 1024; f += 256) {
        u64 a1 = s5[f * 2], a2 = s5[f * 2 + 1];
        double mu = (double)a1 / 64.0;
        double varm = (double)a2 / 64.0 - mu * mu;
        double A = (double)ldin(g5, f, f32) / sqrt(4.0 * varm + 1e-5);
        pq5s[f] = make_double2(-2.0 * A, 2.0 * A * mu + (double)ldin(b5, f, f32));
    }
    __syncthreads();
    if (tid < 32) {
        unsigned mask = 0;
        for (int j = 0; j < 32; j++) {
            int f = tid * 32 + j;
            double2 p = pq5s[f];
            if ((double)acc1[n * 1024 + f] * p.x + p.y > 0.0) mask |= 1u << j;
        }
        xw[tid] = mask;
    }
    __syncthreads();
    int j = blockIdx.x * 256 + tid;
    if (j >= 1000) return;
    unsigned a = 0;
    for (int w = 0; w < 32; w++) a += __popc(xw[w] ^ fc2wp[j * 32 + w]);
    acc2[n * 1000 + j] = (u16)a;
    atomicAdd(&s6[j * 2], (u64)a);
    atomicAdd(&s6[j * 2 + 1], (u64)(a * a));
}

// bn6 (folded from u64 stats) + log_softmax
__global__ void k_lsm(const u16* __restrict__ acc2, const u64* __restrict__ s6,
                      const void* g6, const void* b6, const unsigned* ctl, void* outv) {
    int n = blockIdx.x, tid = threadIdx.x;
    int f32 = ctl[1];
    __shared__ double red[256];
    double v[4];
    double mx = -1e300;
#pragma unroll
    for (int i = 0; i < 4; i++) {
        int j = tid + i * 256;
        if (j < 1000) {
            u64 a1 = s6[j * 2], a2 = s6[j * 2 + 1];
            double mu = (double)a1 / 64.0;
            double varm = (double)a2 / 64.0 - mu * mu;
            double A = (double)ldin(g6, j, f32) / sqrt(4.0 * varm + 1e-5);
            v[i] = (double)acc2[n * 1000 + j] * (-2.0 * A) + (2.0 * A * mu + (double)ldin(b6, j, f32));
            mx = fmax(mx, v[i]);
        } else v[i] = -1e300;
    }
    red[tid] = mx; __syncthreads();
    for (int s = 128; s > 0; s >>= 1) {
        if (tid < s) red[tid] = fmax(red[tid], red[tid + s]);
        __syncthreads();
    }
    mx = red[0]; __syncthreads();
    double sum = 0.0;
#pragma unroll
    for (int i = 0; i < 4; i++) {
        int j = tid + i * 256;
        if (j < 1000) sum += exp(v[i] - mx);
    }
    red[tid] = sum; __syncthreads();
    for (int s = 128; s > 0; s >>= 1) {
        if (tid < s) red[tid] += red[tid + s];
        __syncthreads();
    }
    double ls = log(red[0]);
#pragma unroll
    for (int i = 0; i < 4; i++) {
        int j = tid + i * 256;
        if (j < 1000) {
            float r = (float)(v[i] - mx - ls);
            if (!isfinite(r)) r = -700.0f;
            if (f32) ((float*)outv)[n * 1000 + j] = r;
            else ((bf16*)outv)[n * 1000 + j] = __float2bfloat16(r);
        }
    }
}

extern "C" void kernel_launch(void* const* d_in, const int* in_sizes, int n_in,
                              void* d_out, int out_size, void* d_ws, size_t ws_size,
                              hipStream_t stream) {
    const void* x       = d_in[0];
    const void* bn0_g   = d_in[1];
    const void* bn0_b   = d_in[2];
    const void* conv1_w = d_in[3];
    const void* bn1_g   = d_in[5];
    const void* bn1_b   = d_in[6];
    const void* conv2_w = d_in[7];
    const void* bn2_g   = d_in[9];
    const void* bn2_b   = d_in[10];
    const void* conv3_w = d_in[11];
    const void* bn3_g   = d_in[13];
    const void* bn3_b   = d_in[14];
    const void* conv4_w = d_in[15];
    const void* bn4_g   = d_in[17];
    const void* bn4_b   = d_in[18];
    const void* conv5_w = d_in[19];
    const void* conv5_b = d_in[20];
    const void* fc1_w   = d_in[21];
    const void* bn5_g   = d_in[23];
    const void* bn5_b   = d_in[24];
    const void* fc2_w   = d_in[25];
    const void* bn6_g   = d_in[27];
    const void* bn6_b   = d_in[28];

    char* wsb = (char*)d_ws;
    size_t off = 0;
    auto alloc = [&](size_t bytes) -> void* {
        off = (off + 255) & ~(size_t)255;
        void* p = wsb + off;
        off += bytes;
        return p;
    };

    unsigned* ctl   = (unsigned*)alloc(256);
    unsigned* x2p   = (unsigned*)alloc(2716672);       // 5306*64 uint2
    double*   part1 = (double*)alloc(5439488);         // 64co * 5312 * 2 f64
    u16*      m2    = (u16*)alloc(14270464);
    uint2*    x3p   = (uint2*)alloc(891904);
    u16*      m3    = (u16*)alloc(4538368);
    uint2*    x4p   = (uint2*)alloc(283648);
    u16*      m4    = (u16*)alloc(1294336);
    uint2*    x5p   = (uint2*)alloc(80896);
    u16*      m5    = (u16*)alloc(106496);
    u16*      acc1  = (u16*)alloc(131072);
    u16*      acc2  = (u16*)alloc(128000);
    double*   ws1d  = (double*)alloc(62976);           // 7872 f64 sign weights
    uint2*    w2p   = (uint2*)alloc(20992);
    uint2*    w3p   = (uint2*)alloc(20992);
    uint2*    w4p   = (uint2*)alloc(20992);
    uint2*    w5p   = (uint2*)alloc(10496);
    unsigned* fc1wp = (unsigned*)alloc(106496);
    unsigned* fc2wp = (unsigned*)alloc(128000);
    u64*      stats = (u64*)alloc(12288 * 8);          // s2|s3|s4|s5|s6 (zeroed in prep)
    double*   part0 = (double*)alloc(2048);            // bn0 partials (3*32*2)
    double2*  bnp1  = (double2*)alloc(64 * 16);
    size_t need_small = (off + 255) & ~(size_t)255;
    double*   y64   = (double*)alloc(173867008);       // 64*64*5306 f64
    size_t need_big = (off + 255) & ~(size_t)255;

    u64* s2 = stats;
    u64* s3 = stats + 2048;
    u64* s4 = stats + 4096;
    u64* s5 = stats + 6144;
    u64* s6 = stats + 8192;

    k_probe<<<1, 256, 0, stream>>>(x, ctl);

    if (n_in != 29) {
        k_sentinel<<<250, 256, 0, stream>>>(d_out, ctl, -(3000.0f + (float)n_in));
        return;
    }
    if (ws_size < need_small) {
        k_sentinel<<<250, 256, 0, stream>>>(d_out, ctl, -1500.0f);
        return;
    }
    if (ws_size < need_big) {
        k_sentinel<<<250, 256, 0, stream>>>(d_out, ctl, -1600.0f);
        return;
    }

    // 1 launch: all weight prep + stat zeroing
    k_prep<<<dim3(125, 8), 256, 0, stream>>>(conv1_w, conv2_w, conv3_w, conv4_w, conv5_w,
                                             fc1_w, fc2_w, ws1d, w2p, w3p, w4p, w5p,
                                             fc1wp, fc2wp, stats, ctl);

    // bn0 stats -> conv1 (single pass, fused bn0-fin + bn1 partials) -> bn1 fin -> pack
    k_bn0_stats<<<dim3(32, 3), 256, 0, stream>>>(x, part0, ctl);
    k_conv1_store<<<dim3(83, 64), 256, 0, stream>>>(x, part0, bn0_g, bn0_b, ws1d, y64, part1, ctl);
    k_fin_y<<<64, 256, 0, stream>>>(part1, bn1_g, bn1_b, bnp1, ctl);
    k_pack_y<<<dim3(21, 64), 256, 0, stream>>>(y64, bnp1, (uint2*)x2p);

    // conv2..conv4: conv(+stats) -> pack(+fin)
    k_conv_bin<<<dim3(28, 64, 2), 256, 0, stream>>>((const uint2*)x2p, w2p, m2, 1742, 5306, 64, s2);
    k_pack_m<<<dim3(7, 64), 256, 0, stream>>>(m2, s2, bn2_g, bn2_b, x3p, 1742, 64.0 * 1742.0, ctl);
    k_conv_bin<<<dim3(9, 64, 2), 256, 0, stream>>>(x3p, w3p, m3, 554, 1742, 64, s3);
    k_pack_m<<<dim3(3, 64), 256, 0, stream>>>(m3, s3, bn3_g, bn3_b, x4p, 554, 64.0 * 554.0, ctl);
    k_conv_bin<<<dim3(3, 64, 2), 256, 0, stream>>>(x4p, w4p, m4, 158, 554, 64, s4);
    k_pack_m<<<dim3(1, 64), 256, 0, stream>>>(m4, s4, bn4_g, bn4_b, x5p, 158, 64.0 * 158.0, ctl);

    // conv5 (no BN stats)
    k_conv_bin<<<dim3(1, 64, 1), 256, 0, stream>>>(x5p, w5p, m5, 26, 158, 32, nullptr);

    // fc tail: 3 launches
    k_fc1<<<dim3(4, 64), 256, 0, stream>>>(m5, conv5_b, fc1wp, acc1, s5, ctl);
    k_fc2<<<dim3(4, 64), 256, 0, stream>>>(acc1, s5, bn5_g, bn5_b, fc2wp, acc2, s6, ctl);
    k_lsm<<<64, 256, 0, stream>>>(acc2, s6, bn6_g, bn6_b, ctl, d_out);
}

// Round 6
// 884.784 us; speedup vs baseline: 2.2455x; 1.0436x over previous
//
#include <hip/hip_runtime.h>
#include <hip/hip_bf16.h>
#include <stdint.h>

typedef __hip_bfloat16 bf16;
typedef unsigned long long u64;
typedef unsigned short u16;

static __device__ __forceinline__ float ldin(const void* p, long i, int f32) {
    return f32 ? ((const float*)p)[i] : __bfloat162float(((const bf16*)p)[i]);
}

// ---------------- probe: ctl[0]=0, ctl[1]=f32 flag ----------------
__global__ void k_probe(const void* x, unsigned* ctl) {
    int tid = threadIdx.x;
    int good = 0;
    for (int i = tid; i < 1024; i += 256) {
        float v = __bfloat162float(((const bf16*)x)[2 * i]);
        float a = fabsf(v);
        if (v == 0.0f || (isfinite(v) && a >= 1e-4f && a <= 100.0f)) good++;
    }
    __shared__ int s[256];
    s[tid] = good; __syncthreads();
    for (int st = 128; st > 0; st >>= 1) {
        if (tid < st) s[tid] += s[tid + st];
        __syncthreads();
    }
    if (tid == 0) { ctl[0] = 0u; ctl[1] = (s[0] >= 700) ? 0u : 1u; }
}

__global__ void k_sentinel(void* outv, const unsigned* ctl, float val) {
    int i = blockIdx.x * 256 + threadIdx.x;
    if (i >= 64000) return;
    if (ctl[1]) ((float*)outv)[i] = val;
    else ((bf16*)outv)[i] = __float2bfloat16(val);
}

// ---------------- mega prep: weights + stat zero + bn0 stats ----------------
__device__ __forceinline__ void pack_convw_task(const void* w, uint2* wp, int Co, int f32,
                                                int bx, int tid) {
    int t = bx * 256 + tid;
    if (t >= Co * 41) return;
    int co = t / 41, k = t % 41;
    unsigned w0 = 0, w1 = 0;
    for (int c = 0; c < 32; c++)
        if (ldin(w, (co * 64 + c) * 41 + k, f32) > 0.f) w0 |= (1u << c);
    for (int c = 0; c < 32; c++)
        if (ldin(w, (co * 64 + 32 + c) * 41 + k, f32) > 0.f) w1 |= (1u << c);
    wp[t] = make_uint2(w0, w1);
}
__device__ __forceinline__ void pack_rows_task(const void* w, unsigned* wp, int rows, int F,
                                               int f32, int bx, int tid) {
    int Fw = F >> 5;
    int t = bx * 256 + tid;
    if (t >= rows * Fw) return;
    int r = t / Fw, wi = t % Fw;
    unsigned m = 0;
    for (int j = 0; j < 32; j++)
        if (ldin(w, (long)r * F + wi * 32 + j, f32) > 0.f) m |= (1u << j);
    wp[t] = m;
}

__global__ void k_prep(const void* x, const void* c1w, const void* c2w, const void* c3w,
                       const void* c4w, const void* c5w, const void* f1w, const void* f2w,
                       double* ws1d, uint2* w2p, uint2* w3p, uint2* w4p, uint2* w5p,
                       unsigned* fc1wp, unsigned* fc2wp, u64* stats, double* part0,
                       const unsigned* ctl) {
    int f32 = ctl[1];
    int task = blockIdx.y, bx = blockIdx.x, tid = threadIdx.x;
    switch (task) {
        case 0: {
            int i = bx * 256 + tid;
            if (i < 7872) {
                float v = ldin(c1w, i, f32);
                ws1d[i] = (v > 0.f) ? 1.0 : ((v < 0.f) ? -1.0 : 0.0);
            }
        } break;
        case 1: pack_convw_task(c2w, w2p, 64, f32, bx, tid); break;
        case 2: pack_convw_task(c3w, w3p, 64, f32, bx, tid); break;
        case 3: pack_convw_task(c4w, w4p, 64, f32, bx, tid); break;
        case 4: pack_convw_task(c5w, w5p, 32, f32, bx, tid); break;
        case 5: pack_rows_task(f1w, fc1wp, 1024, 832, f32, bx, tid); break;
        case 6: pack_rows_task(f2w, fc2wp, 1000, 1024, f32, bx, tid); break;
        case 7: {
            int i = bx * 256 + tid;
            if (i < 12288) stats[i] = 0ull;
        } break;
        case 8: {
            if (bx >= 96) return;
            int c = bx >> 5, s = bx & 31;   // matches round-5 (c=blockIdx.y, s=blockIdx.x)
            double s1 = 0, s2 = 0;
            for (int n = 0; n < 64; n++) {
                long base = (long)(n * 3 + c) * 16000;
                for (int l = s * 256 + tid; l < 16000; l += 32 * 256) {
                    double v = (double)ldin(x, base + l, f32);
                    s1 += v; s2 += v * v;
                }
            }
            __shared__ double a1[256], a2[256];
            a1[tid] = s1; a2[tid] = s2;
            __syncthreads();
            for (int st = 128; st > 0; st >>= 1) {
                if (tid < st) { a1[tid] += a1[tid + st]; a2[tid] += a2[tid + st]; }
                __syncthreads();
            }
            if (tid == 0) { part0[(c * 32 + s) * 2] = a1[0]; part0[(c * 32 + s) * 2 + 1] = a2[0]; }
        } break;
    }
}

// ---------------- conv1: dot16, rolling window, launch_bounds(256,4) ----------------
// grid (83, 64); pooled lp = bx*64+lane; tile covers [bx*192, bx*192+272)
__global__ __launch_bounds__(256, 4) void k_conv1(const void* __restrict__ x,
                                                  const double* __restrict__ part0,
                                                  const void* __restrict__ g0,
                                                  const void* __restrict__ b0,
                                                  const double* __restrict__ wsd,
                                                  double* __restrict__ y,
                                                  double* __restrict__ part1,
                                                  const unsigned* __restrict__ ctl) {
    __shared__ double xt[3][272];
    __shared__ double2 b0s[3];
    int f32 = ctl[1];
    int n = blockIdx.y, bx = blockIdx.x, tid = threadIdx.x;
    if (tid < 3) {   // fold bn0 finalize (order matches prior rounds)
        int c = tid;
        double s1 = 0, s2 = 0;
        for (int s = 0; s < 32; s++) { s1 += part0[(c * 32 + s) * 2]; s2 += part0[(c * 32 + s) * 2 + 1]; }
        double M = 64.0 * 16000.0;
        double mu = s1 / M, var = s2 / M - mu * mu;
        double A = (double)ldin(g0, c, f32) / sqrt(var + 1e-5);
        b0s[c] = make_double2(A, (double)ldin(b0, c, f32) - mu * A);
    }
    __syncthreads();
    int base = bx * 192;
    for (int i = tid; i < 816; i += 256) {
        int c = i / 272, j = i % 272;
        int pos = base + j;
        double v = 0.0;
        if (pos < 16000) {
            double2 p = b0s[c];
            v = (double)ldin(x, (long)(n * 3 + c) * 16000 + pos, f32) * p.x + p.y;
            v = fmin(fmax(v, -1.0), 1.0);
        }
        xt[c][j] = v;
    }
    __syncthreads();

    int lane = tid & 63;
    int wave = __builtin_amdgcn_readfirstlane(tid >> 6);
    int co0 = wave * 16;

    double acc[16][3] = {};
#pragma unroll 1
    for (int c = 0; c < 3; c++) {
        const double* xr = &xt[c][3 * lane];
        const double* wr = wsd + co0 * 123 + c * 41;
        double x0 = xr[0];
#pragma unroll 1
        for (int kc = 0; kc < 40; kc += 4) {
#pragma unroll
            for (int kk = 0; kk < 4; kk++) {
                int k = kc + kk;
                double x1 = xr[2 * k + 1];
                double x2 = xr[2 * k + 2];
#pragma unroll
                for (int j = 0; j < 16; j++) {
                    double wv = wr[j * 123 + k];
                    acc[j][0] = fma(wv, x0, acc[j][0]);
                    acc[j][1] = fma(wv, x1, acc[j][1]);
                    acc[j][2] = fma(wv, x2, acc[j][2]);
                }
                x0 = x2;
            }
        }
        double x1 = xr[81], x2 = xr[82];
#pragma unroll
        for (int j = 0; j < 16; j++) {
            double wv = wr[j * 123 + 40];
            acc[j][0] = fma(wv, x0, acc[j][0]);
            acc[j][1] = fma(wv, x1, acc[j][1]);
            acc[j][2] = fma(wv, x2, acc[j][2]);
        }
    }

    int lp = bx * 64 + lane;
    bool ok = lp < 5306;
#pragma unroll
    for (int j = 0; j < 16; j++) {
        double yp = fmax(fmax(acc[j][0], acc[j][1]), acc[j][2]);   // maxpool3 (bias cancels in bn1)
        if (ok) y[((size_t)n * 64 + co0 + j) * 5306 + lp] = yp;
        double s = ok ? yp : 0.0;
        double q = ok ? yp * yp : 0.0;
        for (int off = 32; off > 0; off >>= 1) {
            s += __shfl_down(s, off, 64);
            q += __shfl_down(q, off, 64);
        }
        if (lane == 0) {
            size_t idx = ((size_t)(co0 + j) * 5312 + (size_t)bx * 64 + n) * 2;
            part1[idx] = s; part1[idx + 1] = q;
        }
    }
}

// bn1 finalize: grid 64 blocks
__global__ void k_fin_y(const double* __restrict__ part1, const void* g, const void* b,
                        double2* __restrict__ bnp1, const unsigned* ctl) {
    int f32 = ctl[1];
    int c = blockIdx.x, tid = threadIdx.x;
    double s1 = 0, s2 = 0;
    for (int i = tid; i < 5312; i += 256) {
        s1 += part1[((size_t)c * 5312 + i) * 2];
        s2 += part1[((size_t)c * 5312 + i) * 2 + 1];
    }
    __shared__ double a1[256], a2[256];
    a1[tid] = s1; a2[tid] = s2;
    __syncthreads();
    for (int st = 128; st > 0; st >>= 1) {
        if (tid < st) { a1[tid] += a1[tid + st]; a2[tid] += a2[tid + st]; }
        __syncthreads();
    }
    if (tid == 0) {
        double M = 64.0 * 5306.0;
        double mu = a1[0] / M, var = a2[0] / M - mu * mu;
        double A = (double)ldin(g, c, f32) / sqrt(var + 1e-5);
        bnp1[c] = make_double2(A, (double)ldin(b, c, f32) - mu * A);
    }
}

// pack sign(y*A+B) -> x2p; vectorized 2 positions/thread; grid (11, 64)
__global__ void k_pack_y(const double* __restrict__ y, const double2* __restrict__ bnp1,
                         uint2* __restrict__ xp) {
    int n = blockIdx.y;
    int pr = blockIdx.x * 256 + threadIdx.x;   // pair index, 2653 pairs
    if (pr >= 2653) return;
    unsigned a0 = 0, a1 = 0, b0 = 0, b1 = 0;
    for (int c = 0; c < 64; c++) {
        double2 p = bnp1[c];
        double2 yv = ((const double2*)(y + ((size_t)n * 64 + c) * 5306))[pr];
        unsigned bitc = 1u << (c & 31);
        if (c < 32) {
            if (yv.x * p.x + p.y > 0.0) a0 |= bitc;
            if (yv.y * p.x + p.y > 0.0) b0 |= bitc;
        } else {
            if (yv.x * p.x + p.y > 0.0) a1 |= bitc;
            if (yv.y * p.x + p.y > 0.0) b1 |= bitc;
        }
    }
    uint4 out = make_uint4(a0, a1, b0, b1);   // positions 2*pr, 2*pr+1
    ((uint4*)xp)[(size_t)n * 2653 + pr] = out;
}

// ---------------- binary conv from packed input (conv2) ----------------
__global__ __launch_bounds__(256) void k_conv_bin(const uint2* __restrict__ xp,
                                                  const uint2* __restrict__ wp,
                                                  u16* __restrict__ mout,
                                                  int Lp, int Lin, int Co,
                                                  u64* __restrict__ stat) {
    int n = blockIdx.y, tid = threadIdx.x;
    int lane = tid & 63;
    int wave = __builtin_amdgcn_readfirstlane(tid >> 6);
    int co0 = blockIdx.z * 32 + wave * 8;
    int base = blockIdx.x * 192;
    int lp = blockIdx.x * 64 + lane;

    __shared__ uint2 xt[272];
    for (int i = tid; i < 272; i += 256) {
        int pos = base + i;
        xt[i] = (pos < Lin) ? xp[(size_t)n * Lin + pos] : make_uint2(0u, 0u);
    }
    __syncthreads();

    int acc[8][3] = {};
    uint2 xa = xt[3 * lane];
    for (int k = 0; k < 41; k++) {
        uint2 xb = xt[3 * lane + 2 * k + 1];
        uint2 xc = xt[3 * lane + 2 * k + 2];
#pragma unroll
        for (int j = 0; j < 8; j++) {
            uint2 w = wp[(co0 + j) * 41 + k];
            acc[j][0] += __popc(w.x ^ xa.x) + __popc(w.y ^ xa.y);
            acc[j][1] += __popc(w.x ^ xb.x) + __popc(w.y ^ xb.y);
            acc[j][2] += __popc(w.x ^ xc.x) + __popc(w.y ^ xc.y);
        }
        xa = xc;
    }
    bool ok = lp < Lp;
    int sb = blockIdx.x & 15;
#pragma unroll
    for (int j = 0; j < 8; j++) {
        int m = min(min(acc[j][0], acc[j][1]), acc[j][2]);
        if (ok) mout[((size_t)n * Co + co0 + j) * Lp + lp] = (u16)m;
        if (stat) {
            unsigned s = ok ? (unsigned)m : 0u;
            unsigned q = ok ? (unsigned)(m * m) : 0u;
            for (int off = 32; off > 0; off >>= 1) {
                s += __shfl_down(s, off, 64);
                q += __shfl_down(q, off, 64);
            }
            if (lane == 0) {
                atomicAdd(&stat[((co0 + j) * 16 + sb) * 2], (u64)s);
                atomicAdd(&stat[((co0 + j) * 16 + sb) * 2 + 1], (u64)q);
            }
        }
    }
}

// ---------------- binary conv with fused staging from (m, stats) — conv3/4/5 ----------------
__global__ __launch_bounds__(256) void k_conv_binm(const u16* __restrict__ min_,
                                                   const u64* __restrict__ statIn,
                                                   const void* g, const void* b, double M,
                                                   const uint2* __restrict__ wp,
                                                   u16* __restrict__ mout,
                                                   u64* __restrict__ statOut,
                                                   int Lp, int Lin, int Co,
                                                   const unsigned* __restrict__ ctl) {
    __shared__ double2 pqs[64];
    __shared__ uint2 xt[272];
    int f32 = ctl[1];
    int n = blockIdx.y, tid = threadIdx.x;
    if (tid < 64) {   // BN finalize, identical to round-5 pack_m
        int c = tid;
        u64 s1 = 0, s2 = 0;
        for (int s = 0; s < 16; s++) { s1 += statIn[(c * 16 + s) * 2]; s2 += statIn[(c * 16 + s) * 2 + 1]; }
        double mu = (double)s1 / M;
        double varm = (double)s2 / M - mu * mu;
        double A = (double)ldin(g, c, f32) / sqrt(4.0 * varm + 1e-5);
        pqs[c] = make_double2(-2.0 * A, 2.0 * A * mu + (double)ldin(b, c, f32));
    }
    __syncthreads();
    int base = blockIdx.x * 192;
    for (int i = tid; i < 272; i += 256) {
        int pos = base + i;
        unsigned w0 = 0, w1 = 0;
        if (pos < Lin) {
            const u16* mp = min_ + (size_t)n * 64 * Lin + pos;
#pragma unroll 4
            for (int c = 0; c < 32; c++) {
                double2 p = pqs[c];
                if ((double)mp[(size_t)c * Lin] * p.x + p.y > 0.0) w0 |= 1u << c;
            }
#pragma unroll 4
            for (int c = 0; c < 32; c++) {
                double2 p = pqs[c + 32];
                if ((double)mp[(size_t)(c + 32) * Lin] * p.x + p.y > 0.0) w1 |= 1u << c;
            }
        }
        xt[i] = make_uint2(w0, w1);
    }
    __syncthreads();

    int lane = tid & 63;
    int wave = __builtin_amdgcn_readfirstlane(tid >> 6);
    int co0 = blockIdx.z * 32 + wave * 8;
    int lp = blockIdx.x * 64 + lane;

    int acc[8][3] = {};
    uint2 xa = xt[3 * lane];
    for (int k = 0; k < 41; k++) {
        uint2 xb = xt[3 * lane + 2 * k + 1];
        uint2 xc = xt[3 * lane + 2 * k + 2];
#pragma unroll
        for (int j = 0; j < 8; j++) {
            uint2 w = wp[(co0 + j) * 41 + k];
            acc[j][0] += __popc(w.x ^ xa.x) + __popc(w.y ^ xa.y);
            acc[j][1] += __popc(w.x ^ xb.x) + __popc(w.y ^ xb.y);
            acc[j][2] += __popc(w.x ^ xc.x) + __popc(w.y ^ xc.y);
        }
        xa = xc;
    }
    bool ok = lp < Lp;
    int sb = blockIdx.x & 15;
#pragma unroll
    for (int j = 0; j < 8; j++) {
        int m = min(min(acc[j][0], acc[j][1]), acc[j][2]);
        if (ok) mout[((size_t)n * Co + co0 + j) * Lp + lp] = (u16)m;
        if (statOut) {
            unsigned s = ok ? (unsigned)m : 0u;
            unsigned q = ok ? (unsigned)(m * m) : 0u;
            for (int off = 32; off > 0; off >>= 1) {
                s += __shfl_down(s, off, 64);
                q += __shfl_down(q, off, 64);
            }
            if (lane == 0) {
                atomicAdd(&statOut[((co0 + j) * 16 + sb) * 2], (u64)s);
                atomicAdd(&statOut[((co0 + j) * 16 + sb) * 2 + 1], (u64)q);
            }
        }
    }
}

// ---------------- fc tail ----------------
__global__ void k_fc1(const u16* __restrict__ m5, const void* __restrict__ b5,
                      const unsigned* __restrict__ fc1wp, u16* __restrict__ acc1,
                      u64* __restrict__ s5, const unsigned* ctl) {
    __shared__ unsigned xw[26];
    int f32 = ctl[1];
    int n = blockIdx.y, tid = threadIdx.x;
    if (tid < 26) {
        unsigned mask = 0;
        for (int j = 0; j < 32; j++) {
            int f = tid * 32 + j, c = f / 26, l = f % 26;
            double yv = 2624.0 - 2.0 * (double)m5[(n * 32 + c) * 26 + l] + (double)ldin(b5, c, f32);
            if (yv > 0.0) mask |= 1u << j;
        }
        xw[tid] = mask;
    }
    __syncthreads();
    int j = blockIdx.x * 256 + tid;
    unsigned a = 0;
    for (int w = 0; w < 26; w++) a += __popc(xw[w] ^ fc1wp[j * 26 + w]);
    acc1[n * 1024 + j] = (u16)a;
    atomicAdd(&s5[j * 2], (u64)a);
    atomicAdd(&s5[j * 2 + 1], (u64)(a * a));
}

__global__ void k_fc2(const u16* __restrict__ acc1, const u64* __restrict__ s5,
                      const void* g5, const void* b5, const unsigned* __restrict__ fc2wp,
                      u16* __restrict__ acc2, u64* __restrict__ s6, const unsigned* ctl) {
    __shared__ double2 pq5s[1024];
    __shared__ unsigned xw[32];
    int f32 = ctl[1];
    int n = blockIdx.y, tid = threadIdx.x;
    for (int f = tid; f < 1024; f += 256) {
        u64 a1 = s5[f * 2], a2 = s5[f * 2 + 1];
        double mu = (double)a1 / 64.0;
        double varm = (double)a2 / 64.0 - mu * mu;
        double A = (double)ldin(g5, f, f32) / sqrt(4.0 * varm + 1e-5);
        pq5s[f] = make_double2(-2.0 * A, 2.0 * A * mu + (double)ldin(b5, f, f32));
    }
    __syncthreads();
    if (tid < 32) {
        unsigned mask = 0;
        for (int j = 0; j < 32; j++) {
            int f = tid * 32 + j;
            double2 p = pq5s[f];
            if ((double)acc1[n * 1024 + f] * p.x + p.y > 0.0) mask |= 1u << j;
        }
        xw[tid] = mask;
    }
    __syncthreads();
    int j = blockIdx.x * 256 + tid;
    if (j >= 1000) return;
    unsigned a = 0;
    for (int w = 0; w < 32; w++) a += __popc(xw[w] ^ fc2wp[j * 32 + w]);
    acc2[n * 1000 + j] = (u16)a;
    atomicAdd(&s6[j * 2], (u64)a);
    atomicAdd(&s6[j * 2 + 1], (u64)(a * a));
}

__global__ void k_lsm(const u16* __restrict__ acc2, const u64* __restrict__ s6,
                      const void* g6, const void* b6, const unsigned* ctl, void* outv) {
    int n = blockIdx.x, tid = threadIdx.x;
    int f32 = ctl[1];
    __shared__ double red[256];
    double v[4];
    double mx = -1e300;
#pragma unroll
    for (int i = 0; i < 4; i++) {
        int j = tid + i * 256;
        if (j < 1000) {
            u64 a1 = s6[j * 2], a2 = s6[j * 2 + 1];
            double mu = (double)a1 / 64.0;
            double varm = (double)a2 / 64.0 - mu * mu;
            double A = (double)ldin(g6, j, f32) / sqrt(4.0 * varm + 1e-5);
            v[i] = (double)acc2[n * 1000 + j] * (-2.0 * A) + (2.0 * A * mu + (double)ldin(b6, j, f32));
            mx = fmax(mx, v[i]);
        } else v[i] = -1e300;
    }
    red[tid] = mx; __syncthreads();
    for (int s = 128; s > 0; s >>= 1) {
        if (tid < s) red[tid] = fmax(red[tid], red[tid + s]);
        __syncthreads();
    }
    mx = red[0]; __syncthreads();
    double sum = 0.0;
#pragma unroll
    for (int i = 0; i < 4; i++) {
        int j = tid + i * 256;
        if (j < 1000) sum += exp(v[i] - mx);
    }
    red[tid] = sum; __syncthreads();
    for (int s = 128; s > 0; s >>= 1) {
        if (tid < s) red[tid] += red[tid + s];
        __syncthreads();
    }
    double ls = log(red[0]);
#pragma unroll
    for (int i = 0; i < 4; i++) {
        int j = tid + i * 256;
        if (j < 1000) {
            float r = (float)(v[i] - mx - ls);
            if (!isfinite(r)) r = -700.0f;
            if (f32) ((float*)outv)[n * 1000 + j] = r;
            else ((bf16*)outv)[n * 1000 + j] = __float2bfloat16(r);
        }
    }
}

extern "C" void kernel_launch(void* const* d_in, const int* in_sizes, int n_in,
                              void* d_out, int out_size, void* d_ws, size_t ws_size,
                              hipStream_t stream) {
    const void* x       = d_in[0];
    const void* bn0_g   = d_in[1];
    const void* bn0_b   = d_in[2];
    const void* conv1_w = d_in[3];
    const void* bn1_g   = d_in[5];
    const void* bn1_b   = d_in[6];
    const void* conv2_w = d_in[7];
    const void* bn2_g   = d_in[9];
    const void* bn2_b   = d_in[10];
    const void* conv3_w = d_in[11];
    const void* bn3_g   = d_in[13];
    const void* bn3_b   = d_in[14];
    const void* conv4_w = d_in[15];
    const void* bn4_g   = d_in[17];
    const void* bn4_b   = d_in[18];
    const void* conv5_w = d_in[19];
    const void* conv5_b = d_in[20];
    const void* fc1_w   = d_in[21];
    const void* bn5_g   = d_in[23];
    const void* bn5_b   = d_in[24];
    const void* fc2_w   = d_in[25];
    const void* bn6_g   = d_in[27];
    const void* bn6_b   = d_in[28];

    char* wsb = (char*)d_ws;
    size_t off = 0;
    auto alloc = [&](size_t bytes) -> void* {
        off = (off + 255) & ~(size_t)255;
        void* p = wsb + off;
        off += bytes;
        return p;
    };

    unsigned* ctl   = (unsigned*)alloc(256);
    unsigned* x2p   = (unsigned*)alloc(2716672);       // 5306*64 uint2
    double*   part1 = (double*)alloc(5439488);         // 64 * 5312 * 2 f64
    u16*      m2    = (u16*)alloc(14270464);
    u16*      m3    = (u16*)alloc(4538368);
    u16*      m4    = (u16*)alloc(1294336);
    u16*      m5    = (u16*)alloc(106496);
    u16*      acc1  = (u16*)alloc(131072);
    u16*      acc2  = (u16*)alloc(128000);
    double*   ws1d  = (double*)alloc(62976);
    uint2*    w2p   = (uint2*)alloc(20992);
    uint2*    w3p   = (uint2*)alloc(20992);
    uint2*    w4p   = (uint2*)alloc(20992);
    uint2*    w5p   = (uint2*)alloc(10496);
    unsigned* fc1wp = (unsigned*)alloc(106496);
    unsigned* fc2wp = (unsigned*)alloc(128000);
    u64*      stats = (u64*)alloc(12288 * 8);          // s2|s3|s4|s5|s6 zeroed in prep
    double*   part0 = (double*)alloc(2048);
    double2*  bnp1  = (double2*)alloc(64 * 16);
    double*   y64   = (double*)alloc(173867008);       // 64*64*5306 f64
    size_t need = (off + 255) & ~(size_t)255;

    u64* s2 = stats;
    u64* s3 = stats + 2048;
    u64* s4 = stats + 4096;
    u64* s5 = stats + 6144;
    u64* s6 = stats + 8192;

    k_probe<<<1, 256, 0, stream>>>(x, ctl);

    if (n_in != 29) {
        k_sentinel<<<250, 256, 0, stream>>>(d_out, ctl, -(3000.0f + (float)n_in));
        return;
    }
    if (ws_size < need) {
        k_sentinel<<<250, 256, 0, stream>>>(d_out, ctl, -1500.0f);
        return;
    }

    // prep: weights + stat zero + bn0 stats (9 tasks, 1 launch)
    k_prep<<<dim3(125, 9), 256, 0, stream>>>(x, conv1_w, conv2_w, conv3_w, conv4_w, conv5_w,
                                             fc1_w, fc2_w, ws1d, w2p, w3p, w4p, w5p,
                                             fc1wp, fc2wp, stats, part0, ctl);

    // conv1 (dot16, fused bn0-fin + bn1 partials) -> bn1 fin -> pack
    k_conv1<<<dim3(83, 64), 256, 0, stream>>>(x, part0, bn0_g, bn0_b, ws1d, y64, part1, ctl);
    k_fin_y<<<64, 256, 0, stream>>>(part1, bn1_g, bn1_b, bnp1, ctl);
    k_pack_y<<<dim3(11, 64), 256, 0, stream>>>(y64, bnp1, (uint2*)x2p);

    // conv2 from packed input (+s2 stats)
    k_conv_bin<<<dim3(28, 64, 2), 256, 0, stream>>>((const uint2*)x2p, w2p, m2, 1742, 5306, 64, s2);

    // conv3/4/5: staging fused with BN(m)+pack
    k_conv_binm<<<dim3(9, 64, 2), 256, 0, stream>>>(m2, s2, bn2_g, bn2_b, 64.0 * 1742.0,
                                                    w3p, m3, s3, 554, 1742, 64, ctl);
    k_conv_binm<<<dim3(3, 64, 2), 256, 0, stream>>>(m3, s3, bn3_g, bn3_b, 64.0 * 554.0,
                                                    w4p, m4, s4, 158, 554, 64, ctl);
    k_conv_binm<<<dim3(1, 64, 1), 256, 0, stream>>>(m4, s4, bn4_g, bn4_b, 64.0 * 158.0,
                                                    w5p, m5, nullptr, 26, 158, 32, ctl);

    // fc tail
    k_fc1<<<dim3(4, 64), 256, 0, stream>>>(m5, conv5_b, fc1wp, acc1, s5, ctl);
    k_fc2<<<dim3(4, 64), 256, 0, stream>>>(acc1, s5, bn5_g, bn5_b, fc2wp, acc2, s6, ctl);
    k_lsm<<<64, 256, 0, stream>>>(acc2, s6, bn6_g, bn6_b, ctl, d_out);
}